// Round 1
// baseline (208.336 us; speedup 1.0000x reference)
//
#include <hip/hip_runtime.h>
#include <hip/hip_bf16.h>
#include <stdint.h>

#define DIM     1024
#define DINNER  2048
#define BATCH   4096
#define LN_EPS  1e-5f

typedef unsigned short u16;
using f32x4  = __attribute__((ext_vector_type(4))) float;
using bf16x8 = __attribute__((ext_vector_type(8))) __bf16;

__device__ __forceinline__ float bf2f(u16 h) {
    union { unsigned u; float f; } v; v.u = ((unsigned)h) << 16; return v.f;
}
__device__ __forceinline__ u16 f2bf(float f) {
    union { float f; unsigned u; } v; v.f = f;
    unsigned r = v.u + 0x7fffu + ((v.u >> 16) & 1u);
    return (u16)(r >> 16);
}
__device__ __forceinline__ float silu_f(float x) {
    return x / (1.f + __expf(-x));
}

// ---------------- fp32 -> bf16 weight conversion ----------------
__global__ void cvt_bf16_kernel(const float* __restrict__ in, u16* __restrict__ out, int n) {
    int i = blockIdx.x * blockDim.x + threadIdx.x;
    int stride = gridDim.x * blockDim.x;
    for (; i < n; i += stride) out[i] = f2bf(in[i]);
}

// ---------------- LayerNorm: x (4096x1024 f32) -> xn (bf16) ----------------
__global__ __launch_bounds__(256)
void ln_kernel(const float* __restrict__ x, const float* __restrict__ gamma,
               const float* __restrict__ beta, u16* __restrict__ xn) {
    const int row = blockIdx.x;
    const int t = threadIdx.x;
    float4 v = ((const float4*)(x + (size_t)row * DIM))[t];
    float s1 = v.x + v.y + v.z + v.w;
    float s2 = v.x*v.x + v.y*v.y + v.z*v.z + v.w*v.w;
    #pragma unroll
    for (int o = 32; o > 0; o >>= 1) {
        s1 += __shfl_down(s1, o);
        s2 += __shfl_down(s2, o);
    }
    __shared__ float red[8];
    __shared__ float mv[2];
    const int w = t >> 6, l = t & 63;
    if (l == 0) { red[w] = s1; red[4 + w] = s2; }
    __syncthreads();
    if (t == 0) {
        float a = red[0] + red[1] + red[2] + red[3];
        float b = red[4] + red[5] + red[6] + red[7];
        float mu = a * (1.f / DIM);
        float var = b * (1.f / DIM) - mu * mu;
        mv[0] = mu; mv[1] = rsqrtf(var + LN_EPS);
    }
    __syncthreads();
    const float mu = mv[0], rs = mv[1];
    float4 g  = ((const float4*)gamma)[t];
    float4 be = ((const float4*)beta)[t];
    ushort4 o = make_ushort4(
        f2bf((v.x - mu) * rs * g.x + be.x),
        f2bf((v.y - mu) * rs * g.y + be.y),
        f2bf((v.z - mu) * rs * g.z + be.z),
        f2bf((v.w - mu) * rs * g.w + be.w));
    *(ushort4*)(xn + (size_t)row * DIM + t * 4) = o;
}

// ---------------- 128x128 bt-GEMM (C = A * B^T), bf16 in, MFMA ----------------
// EPI 0: write fp32 to outf (GEMM4 -> d_out)
// EPI 1: GEMM1 epilogue: col<2048 -> xc = silu(conv_b + conv_w[:,3]*v); else sz = silu(v)
template<int EPI>
__global__ __launch_bounds__(256)
void gemm_bt128(const u16* __restrict__ A, const u16* __restrict__ B,
                int M, int N, int K,
                float* __restrict__ outf,
                u16* __restrict__ xc, u16* __restrict__ sz,
                const float* __restrict__ conv_w, const float* __restrict__ conv_b)
{
    __shared__ u16 As[128 * 64];
    __shared__ u16 Bs[128 * 64];
    const int t = threadIdx.x;
    const int w = t >> 6, l = t & 63;
    const int wr = w >> 1, wc = w & 1;
    const int brow = blockIdx.y * 128, bcol = blockIdx.x * 128;
    const int lr = l & 15;
    const int lk = (l >> 4) * 8;

    f32x4 acc[4][4] = {};

    for (int k0 = 0; k0 < K; k0 += 64) {
        #pragma unroll
        for (int c = 0; c < 4; ++c) {
            const int seg = c * 4 + w;
            const int off = seg * 512 + l * 8;
            const int row = off >> 6, kk = off & 63;
            __builtin_amdgcn_global_load_lds(
                (const __attribute__((address_space(1))) void*)(A + (size_t)(brow + row) * K + (k0 + kk)),
                (__attribute__((address_space(3))) void*)(&As[seg * 512]), 16, 0, 0);
            __builtin_amdgcn_global_load_lds(
                (const __attribute__((address_space(1))) void*)(B + (size_t)(bcol + row) * K + (k0 + kk)),
                (__attribute__((address_space(3))) void*)(&Bs[seg * 512]), 16, 0, 0);
        }
        __syncthreads();
        #pragma unroll
        for (int kk = 0; kk < 2; ++kk) {
            bf16x8 af[4], bfr[4];
            #pragma unroll
            for (int m = 0; m < 4; ++m)
                af[m] = *(const bf16x8*)(&As[(wr * 64 + m * 16 + lr) * 64 + kk * 32 + lk]);
            #pragma unroll
            for (int n = 0; n < 4; ++n)
                bfr[n] = *(const bf16x8*)(&Bs[(wc * 64 + n * 16 + lr) * 64 + kk * 32 + lk]);
            #pragma unroll
            for (int m = 0; m < 4; ++m)
                #pragma unroll
                for (int n = 0; n < 4; ++n)
                    acc[m][n] = __builtin_amdgcn_mfma_f32_16x16x32_bf16(af[m], bfr[n], acc[m][n], 0, 0, 0);
        }
        __syncthreads();
    }

    const int r0 = brow + wr * 64;
    const int c0 = bcol + wc * 64;
    #pragma unroll
    for (int m = 0; m < 4; ++m)
        #pragma unroll
        for (int n = 0; n < 4; ++n)
            #pragma unroll
            for (int r = 0; r < 4; ++r) {
                const int row = r0 + m * 16 + (l >> 4) * 4 + r;
                const int col = c0 + n * 16 + lr;
                float v = acc[m][n][r];
                if (EPI == 0) {
                    outf[(size_t)row * N + col] = v;
                } else {
                    if (col < DINNER) {
                        float xcv = silu_f(conv_b[col] + conv_w[col * 4 + 3] * v);
                        xc[(size_t)row * DINNER + col] = f2bf(xcv);
                    } else {
                        sz[(size_t)row * DINNER + (col - DINNER)] = f2bf(silu_f(v));
                    }
                }
            }
}

// ---------------- GEMM2: xdb (4096x96) = xc (4096x2048) @ W_xproj^T ----------------
__global__ __launch_bounds__(256)
void gemm_xproj(const u16* __restrict__ xcb, const u16* __restrict__ Wx,
                u16* __restrict__ xdb)
{
    __shared__ u16 Xs[64 * 64];
    __shared__ u16 Ws[96 * 64];
    const int t = threadIdx.x;
    const int w = t >> 6, l = t & 63;
    const int brow = blockIdx.x * 64;
    const int lr = l & 15, lk = (l >> 4) * 8;

    f32x4 acc[6] = {};

    for (int k0 = 0; k0 < DINNER; k0 += 64) {
        #pragma unroll
        for (int c = 0; c < 2; ++c) {
            const int seg = c * 4 + w;
            const int off = seg * 512 + l * 8;
            const int row = off >> 6, kk = off & 63;
            __builtin_amdgcn_global_load_lds(
                (const __attribute__((address_space(1))) void*)(xcb + (size_t)(brow + row) * DINNER + (k0 + kk)),
                (__attribute__((address_space(3))) void*)(&Xs[seg * 512]), 16, 0, 0);
        }
        #pragma unroll
        for (int c = 0; c < 3; ++c) {
            const int seg = c * 4 + w;
            const int off = seg * 512 + l * 8;
            const int row = off >> 6, kk = off & 63;
            __builtin_amdgcn_global_load_lds(
                (const __attribute__((address_space(1))) void*)(Wx + (size_t)row * DINNER + (k0 + kk)),
                (__attribute__((address_space(3))) void*)(&Ws[seg * 512]), 16, 0, 0);
        }
        __syncthreads();
        #pragma unroll
        for (int kk = 0; kk < 2; ++kk) {
            bf16x8 a = *(const bf16x8*)(&Xs[(w * 16 + lr) * 64 + kk * 32 + lk]);
            #pragma unroll
            for (int n = 0; n < 6; ++n) {
                bf16x8 b = *(const bf16x8*)(&Ws[(n * 16 + lr) * 64 + kk * 32 + lk]);
                acc[n] = __builtin_amdgcn_mfma_f32_16x16x32_bf16(a, b, acc[n], 0, 0, 0);
            }
        }
        __syncthreads();
    }
    #pragma unroll
    for (int n = 0; n < 6; ++n)
        #pragma unroll
        for (int r = 0; r < 4; ++r) {
            const int row = brow + w * 16 + (l >> 4) * 4 + r;
            const int col = n * 16 + lr;
            xdb[(size_t)row * 96 + col] = f2bf(acc[n][r]);
        }
}

// ---------------- s[b] = sum_n B[b,n]*C[b,n] ----------------
__global__ void s_kernel(const u16* __restrict__ xdb, float* __restrict__ s)
{
    int b = blockIdx.x * blockDim.x + threadIdx.x;
    if (b >= BATCH) return;
    const u16* p = xdb + (size_t)b * 96;
    float acc = 0.f;
    #pragma unroll
    for (int n = 0; n < 16; ++n)
        acc += bf2f(p[64 + n]) * bf2f(p[80 + n]);
    s[b] = acc;
}

// ---------------- GEMM3 + y epilogue ----------------
// dt_in = xdb[:, :64] @ W_dt^T ; dt = softplus(dt_in + b_dt)
// y = xc * (dt*s + Dskip) * sz   (bf16 out, 4096x2048)
__global__ __launch_bounds__(256)
void gemm_dt_y(const u16* __restrict__ xdb, const u16* __restrict__ Wdt,
               const float* __restrict__ b_dt, const float* __restrict__ Dskip,
               const float* __restrict__ s,
               const u16* __restrict__ xcb, const u16* __restrict__ szb,
               u16* __restrict__ y)
{
    __shared__ u16 Ds[64 * 64];
    __shared__ u16 Ws[128 * 64];
    const int t = threadIdx.x;
    const int w = t >> 6, l = t & 63;
    const int wr = w >> 1, wc = w & 1;
    const int brow = blockIdx.y * 64;
    const int bcol = blockIdx.x * 128;
    const int lr = l & 15, lk = (l >> 4) * 8;

    #pragma unroll
    for (int c = 0; c < 2; ++c) {
        const int seg = c * 4 + w;
        const int off = seg * 512 + l * 8;
        const int row = off >> 6, kk = off & 63;
        __builtin_amdgcn_global_load_lds(
            (const __attribute__((address_space(1))) void*)(xdb + (size_t)(brow + row) * 96 + kk),
            (__attribute__((address_space(3))) void*)(&Ds[seg * 512]), 16, 0, 0);
    }
    #pragma unroll
    for (int c = 0; c < 4; ++c) {
        const int seg = c * 4 + w;
        const int off = seg * 512 + l * 8;
        const int row = off >> 6, kk = off & 63;
        __builtin_amdgcn_global_load_lds(
            (const __attribute__((address_space(1))) void*)(Wdt + (size_t)(bcol + row) * 64 + kk),
            (__attribute__((address_space(3))) void*)(&Ws[seg * 512]), 16, 0, 0);
    }
    __syncthreads();

    f32x4 acc[2][4] = {};
    #pragma unroll
    for (int kk = 0; kk < 2; ++kk) {
        bf16x8 a[2], b[4];
        #pragma unroll
        for (int m = 0; m < 2; ++m)
            a[m] = *(const bf16x8*)(&Ds[(wr * 32 + m * 16 + lr) * 64 + kk * 32 + lk]);
        #pragma unroll
        for (int n = 0; n < 4; ++n)
            b[n] = *(const bf16x8*)(&Ws[(wc * 64 + n * 16 + lr) * 64 + kk * 32 + lk]);
        #pragma unroll
        for (int m = 0; m < 2; ++m)
            #pragma unroll
            for (int n = 0; n < 4; ++n)
                acc[m][n] = __builtin_amdgcn_mfma_f32_16x16x32_bf16(a[m], b[n], acc[m][n], 0, 0, 0);
    }

    #pragma unroll
    for (int m = 0; m < 2; ++m)
        #pragma unroll
        for (int n = 0; n < 4; ++n)
            #pragma unroll
            for (int r = 0; r < 4; ++r) {
                const int row = brow + wr * 32 + m * 16 + (l >> 4) * 4 + r; // batch idx
                const int col = bcol + wc * 64 + n * 16 + lr;               // d idx
                float v = acc[m][n][r] + b_dt[col];
                float dt = (v > 20.f) ? v : log1pf(__expf(v));
                float xcv = bf2f(xcb[(size_t)row * DINNER + col]);
                float szv = bf2f(szb[(size_t)row * DINNER + col]);
                float yv = (dt * s[row] + Dskip[col]) * xcv * szv;
                y[(size_t)row * DINNER + col] = f2bf(yv);
            }
}

extern "C" void kernel_launch(void* const* d_in, const int* in_sizes, int n_in,
                              void* d_out, int out_size, void* d_ws, size_t ws_size,
                              hipStream_t stream) {
    const float* x      = (const float*)d_in[0];
    const float* ln_g   = (const float*)d_in[1];
    const float* ln_b   = (const float*)d_in[2];
    const float* W_in   = (const float*)d_in[3];
    const float* conv_w = (const float*)d_in[4];
    const float* conv_b = (const float*)d_in[5];
    const float* W_xp   = (const float*)d_in[6];
    const float* W_dt   = (const float*)d_in[7];
    const float* b_dt   = (const float*)d_in[8];
    // d_in[9] = A_log : dead (L=1, h0=0)
    const float* Dskip  = (const float*)d_in[10];
    const float* W_out  = (const float*)d_in[11];
    float* out = (float*)d_out;

    char* ws = (char*)d_ws;
    size_t o = 0;
    auto alloc = [&](size_t bytes) {
        void* p = ws + o;
        o = (o + bytes + 255) & ~(size_t)255;
        return p;
    };
    u16* W_in_b  = (u16*)alloc((size_t)2 * DINNER * DIM * 2);   // 4096x1024
    u16* W_out_b = (u16*)alloc((size_t)DIM * DINNER * 2);       // 1024x2048
    u16* W_xp_b  = (u16*)alloc((size_t)96 * DINNER * 2);        // 96x2048
    u16* W_dt_b  = (u16*)alloc((size_t)DINNER * 64 * 2);        // 2048x64
    u16* xn      = (u16*)alloc((size_t)BATCH * DIM * 2);
    u16* xcb     = (u16*)alloc((size_t)BATCH * DINNER * 2);
    u16* szb     = (u16*)alloc((size_t)BATCH * DINNER * 2);
    u16* xdbb    = (u16*)alloc((size_t)BATCH * 96 * 2);
    float* sbuf  = (float*)alloc((size_t)BATCH * 4);
    u16* yb      = (u16*)alloc((size_t)BATCH * DINNER * 2);

    cvt_bf16_kernel<<<1024, 256, 0, stream>>>(W_in,  W_in_b,  2 * DINNER * DIM);
    cvt_bf16_kernel<<<1024, 256, 0, stream>>>(W_out, W_out_b, DIM * DINNER);
    cvt_bf16_kernel<<<256,  256, 0, stream>>>(W_xp,  W_xp_b,  96 * DINNER);
    cvt_bf16_kernel<<<256,  256, 0, stream>>>(W_dt,  W_dt_b,  DINNER * 64);

    ln_kernel<<<BATCH, 256, 0, stream>>>(x, ln_g, ln_b, xn);

    // GEMM1: xz = xn @ W_in^T  (fused conv+silu epilogue -> xc, sz)
    gemm_bt128<1><<<dim3(4096 / 128, BATCH / 128), 256, 0, stream>>>(
        xn, W_in_b, BATCH, 2 * DINNER, DIM, nullptr, xcb, szb, conv_w, conv_b);

    // GEMM2: xdb = xc @ W_xproj^T
    gemm_xproj<<<BATCH / 64, 256, 0, stream>>>(xcb, W_xp_b, xdbb);

    // s[b] = B . C
    s_kernel<<<BATCH / 256, 256, 0, stream>>>(xdbb, sbuf);

    // GEMM3 + epilogue: y
    gemm_dt_y<<<dim3(DINNER / 128, BATCH / 64), 256, 0, stream>>>(
        xdbb, W_dt_b, b_dt, Dskip, sbuf, xcb, szb, yb);

    // GEMM4: out = y @ W_out^T  (fp32)
    gemm_bt128<0><<<dim3(DIM / 128, BATCH / 128), 256, 0, stream>>>(
        yb, W_out_b, BATCH, DIM, DINNER, out, nullptr, nullptr, nullptr, nullptr);
}

// Round 2
// 184.041 us; speedup vs baseline: 1.1320x; 1.1320x over previous
//
#include <hip/hip_runtime.h>
#include <hip/hip_bf16.h>
#include <stdint.h>

#define DIM     1024
#define DINNER  2048
#define BATCH   4096
#define LN_EPS  1e-5f

typedef unsigned short u16;
using f32x4  = __attribute__((ext_vector_type(4))) float;
using bf16x8 = __attribute__((ext_vector_type(8))) __bf16;

__device__ __forceinline__ float bf2f(u16 h) {
    union { unsigned u; float f; } v; v.u = ((unsigned)h) << 16; return v.f;
}
__device__ __forceinline__ u16 f2bf(float f) {
    union { float f; unsigned u; } v; v.f = f;
    unsigned r = v.u + 0x7fffu + ((v.u >> 16) & 1u);
    return (u16)(r >> 16);
}
__device__ __forceinline__ float silu_f(float x) {
    return x / (1.f + __expf(-x));
}

// ---------------- fused fp32 -> bf16 weight conversion (4 regions, float4) ----
__global__ void cvt_all(const float4* __restrict__ s0, ushort4* __restrict__ d0, int n0,
                        const float4* __restrict__ s1, ushort4* __restrict__ d1, int n1,
                        const float4* __restrict__ s2, ushort4* __restrict__ d2, int n2,
                        const float4* __restrict__ s3, ushort4* __restrict__ d3, int n3) {
    int i = blockIdx.x * blockDim.x + threadIdx.x;
    const int stride = gridDim.x * blockDim.x;
    const int total = n0 + n1 + n2 + n3;
    for (; i < total; i += stride) {
        int j = i; const float4* s; ushort4* d;
        if (j < n0) { s = s0; d = d0; }
        else { j -= n0;
            if (j < n1) { s = s1; d = d1; }
            else { j -= n1;
                if (j < n2) { s = s2; d = d2; }
                else { j -= n2; s = s3; d = d3; }
            }
        }
        float4 v = s[j];
        d[j] = make_ushort4(f2bf(v.x), f2bf(v.y), f2bf(v.z), f2bf(v.w));
    }
}

// ---------------- LayerNorm: x (4096x1024 f32) -> xn (bf16) ----------------
__global__ __launch_bounds__(256)
void ln_kernel(const float* __restrict__ x, const float* __restrict__ gamma,
               const float* __restrict__ beta, u16* __restrict__ xn) {
    const int row = blockIdx.x;
    const int t = threadIdx.x;
    float4 v = ((const float4*)(x + (size_t)row * DIM))[t];
    float s1 = v.x + v.y + v.z + v.w;
    float s2 = v.x*v.x + v.y*v.y + v.z*v.z + v.w*v.w;
    #pragma unroll
    for (int o = 32; o > 0; o >>= 1) {
        s1 += __shfl_down(s1, o);
        s2 += __shfl_down(s2, o);
    }
    __shared__ float red[8];
    __shared__ float mv[2];
    const int w = t >> 6, l = t & 63;
    if (l == 0) { red[w] = s1; red[4 + w] = s2; }
    __syncthreads();
    if (t == 0) {
        float a = red[0] + red[1] + red[2] + red[3];
        float b = red[4] + red[5] + red[6] + red[7];
        float mu = a * (1.f / DIM);
        float var = b * (1.f / DIM) - mu * mu;
        mv[0] = mu; mv[1] = rsqrtf(var + LN_EPS);
    }
    __syncthreads();
    const float mu = mv[0], rs = mv[1];
    float4 g  = ((const float4*)gamma)[t];
    float4 be = ((const float4*)beta)[t];
    ushort4 o = make_ushort4(
        f2bf((v.x - mu) * rs * g.x + be.x),
        f2bf((v.y - mu) * rs * g.y + be.y),
        f2bf((v.z - mu) * rs * g.z + be.z),
        f2bf((v.w - mu) * rs * g.w + be.w));
    *(ushort4*)(xn + (size_t)row * DIM + t * 4) = o;
}

// ---------------- bt-GEMM (C = A * B^T), bf16 in, MFMA, XOR-swizzled LDS ----
// Tile: 128 x BN (BN = 128 or 64), BK = 64.
// Swizzle scheme (rule 21 both-sides): LDS dest linear (global_load_lds),
// per-lane GLOBAL source chunk pre-swizzled chunk^=(row&7); reads use same XOR.
// EPI 0: write fp32 to outf (GEMM4 -> d_out)
// EPI 1: GEMM1 epilogue: col<2048 -> xc = silu(conv_b + conv_w[:,3]*v); else sz = silu(v)
template<int EPI, int BN>
__global__ __launch_bounds__(256)
void gemm_bt(const u16* __restrict__ A, const u16* __restrict__ B,
             int N, int K,
             float* __restrict__ outf,
             u16* __restrict__ xc, u16* __restrict__ sz,
             const float* __restrict__ conv_w, const float* __restrict__ conv_b)
{
    constexpr int MR = (BN == 128) ? 4 : 2;   // 16-row fragments per wave
    constexpr int BSEGC = BN / 32;            // B staging c-loop count
    __shared__ u16 As[128 * 64];
    __shared__ u16 Bs[BN * 64];
    const int t = threadIdx.x;
    const int w = t >> 6, l = t & 63;
    const int wr = (BN == 128) ? (w >> 1) : w;
    const int wc = (BN == 128) ? (w & 1) : 0;
    const int brow = blockIdx.y * 128, bcol = blockIdx.x * BN;
    const int lr = l & 15;
    const int l16 = l >> 4;
    const int skk = ((l & 7) ^ (l >> 3)) * 8;   // swizzled source k-offset (lane-const)

    const u16* Abase = A + (size_t)(brow + (l >> 3)) * K + skk;
    const u16* Bbase = B + (size_t)(bcol + (l >> 3)) * K + skk;

    f32x4 acc[MR][4] = {};

    for (int k0 = 0; k0 < K; k0 += 64) {
        #pragma unroll
        for (int c = 0; c < 4; ++c) {
            const int seg = c * 4 + w;
            __builtin_amdgcn_global_load_lds(
                (const __attribute__((address_space(1))) void*)(Abase + (size_t)seg * 8 * K + k0),
                (__attribute__((address_space(3))) void*)(&As[seg * 512]), 16, 0, 0);
        }
        #pragma unroll
        for (int c = 0; c < BSEGC; ++c) {
            const int seg = c * 4 + w;
            __builtin_amdgcn_global_load_lds(
                (const __attribute__((address_space(1))) void*)(Bbase + (size_t)seg * 8 * K + k0),
                (__attribute__((address_space(3))) void*)(&Bs[seg * 512]), 16, 0, 0);
        }
        __syncthreads();
        #pragma unroll
        for (int kk = 0; kk < 2; ++kk) {
            bf16x8 af[MR], bfr[4];
            #pragma unroll
            for (int m = 0; m < MR; ++m) {
                const int r = wr * (16 * MR) + m * 16 + lr;
                af[m] = *(const bf16x8*)(&As[r * 64 + (((kk * 4 + l16) ^ (r & 7)) * 8)]);
            }
            #pragma unroll
            for (int n = 0; n < 4; ++n) {
                const int r = wc * 64 + n * 16 + lr;
                bfr[n] = *(const bf16x8*)(&Bs[r * 64 + (((kk * 4 + l16) ^ (r & 7)) * 8)]);
            }
            #pragma unroll
            for (int m = 0; m < MR; ++m)
                #pragma unroll
                for (int n = 0; n < 4; ++n)
                    acc[m][n] = __builtin_amdgcn_mfma_f32_16x16x32_bf16(af[m], bfr[n], acc[m][n], 0, 0, 0);
        }
        __syncthreads();
    }

    const int r0 = brow + wr * (16 * MR);
    const int c0 = bcol + wc * 64;
    #pragma unroll
    for (int m = 0; m < MR; ++m)
        #pragma unroll
        for (int n = 0; n < 4; ++n)
            #pragma unroll
            for (int r = 0; r < 4; ++r) {
                const int row = r0 + m * 16 + l16 * 4 + r;
                const int col = c0 + n * 16 + lr;
                float v = acc[m][n][r];
                if (EPI == 0) {
                    outf[(size_t)row * N + col] = v;
                } else {
                    if (col < DINNER) {
                        float xcv = silu_f(conv_b[col] + conv_w[col * 4 + 3] * v);
                        xc[(size_t)row * DINNER + col] = f2bf(xcv);
                    } else {
                        sz[(size_t)row * DINNER + (col - DINNER)] = f2bf(silu_f(v));
                    }
                }
            }
}

// ---------------- GEMM2 split-K: P[ks][96][4096] partials (fp32) ----------------
// grid (BATCH/64, 4); block covers 64 rows x 96 cols x 512 K-slice.
__global__ __launch_bounds__(256)
void gemm_xproj(const u16* __restrict__ xcb, const u16* __restrict__ Wx,
                float* __restrict__ P)
{
    __shared__ u16 Xs[64 * 64];
    __shared__ u16 Ws[96 * 64];
    const int t = threadIdx.x, w = t >> 6, l = t & 63;
    const int brow = blockIdx.x * 64;
    const int ks = blockIdx.y;
    const int lr = l & 15, l16 = l >> 4;
    const int skk = ((l & 7) ^ (l >> 3)) * 8;
    const u16* Xbase = xcb + (size_t)(brow + (l >> 3)) * DINNER + skk;
    const u16* Wbase = Wx + (size_t)(l >> 3) * DINNER + skk;

    f32x4 acc[6] = {};
    const int kend = ks * 512 + 512;
    for (int k0 = ks * 512; k0 < kend; k0 += 64) {
        #pragma unroll
        for (int c = 0; c < 2; ++c) {
            const int seg = c * 4 + w;
            __builtin_amdgcn_global_load_lds(
                (const __attribute__((address_space(1))) void*)(Xbase + (size_t)seg * 8 * DINNER + k0),
                (__attribute__((address_space(3))) void*)(&Xs[seg * 512]), 16, 0, 0);
        }
        #pragma unroll
        for (int c = 0; c < 3; ++c) {
            const int seg = c * 4 + w;
            __builtin_amdgcn_global_load_lds(
                (const __attribute__((address_space(1))) void*)(Wbase + (size_t)seg * 8 * DINNER + k0),
                (__attribute__((address_space(3))) void*)(&Ws[seg * 512]), 16, 0, 0);
        }
        __syncthreads();
        #pragma unroll
        for (int kk = 0; kk < 2; ++kk) {
            const int ra = w * 16 + lr;
            bf16x8 a = *(const bf16x8*)(&Xs[ra * 64 + (((kk * 4 + l16) ^ (ra & 7)) * 8)]);
            #pragma unroll
            for (int n = 0; n < 6; ++n) {
                const int rb = n * 16 + lr;
                bf16x8 b = *(const bf16x8*)(&Ws[rb * 64 + (((kk * 4 + l16) ^ (rb & 7)) * 8)]);
                acc[n] = __builtin_amdgcn_mfma_f32_16x16x32_bf16(a, b, acc[n], 0, 0, 0);
            }
        }
        __syncthreads();
    }
    #pragma unroll
    for (int n = 0; n < 6; ++n)
        #pragma unroll
        for (int r = 0; r < 4; ++r) {
            const int row = brow + w * 16 + l16 * 4 + r;
            const int col = n * 16 + lr;
            P[((size_t)ks * 96 + col) * BATCH + row] = acc[n][r];
        }
}

// ---------------- finish: sum partials -> dtb (bf16), s[b] ----------------
__global__ __launch_bounds__(256)
void finish_xdb(const float* __restrict__ P, u16* __restrict__ dtb, float* __restrict__ sbuf)
{
    const int b = blockIdx.x * 256 + threadIdx.x;   // 4096 threads total
    #pragma unroll 8
    for (int c = 0; c < 64; ++c) {
        float v = P[((size_t)0 * 96 + c) * BATCH + b] + P[((size_t)1 * 96 + c) * BATCH + b]
                + P[((size_t)2 * 96 + c) * BATCH + b] + P[((size_t)3 * 96 + c) * BATCH + b];
        dtb[(size_t)b * 64 + c] = f2bf(v);
    }
    float s = 0.f;
    for (int n = 0; n < 16; ++n) {
        float Bv = 0.f, Cv = 0.f;
        #pragma unroll
        for (int ks = 0; ks < 4; ++ks) {
            Bv += P[((size_t)ks * 96 + 64 + n) * BATCH + b];
            Cv += P[((size_t)ks * 96 + 80 + n) * BATCH + b];
        }
        s += Bv * Cv;
    }
    sbuf[b] = s;
}

// ---------------- GEMM3 + y epilogue ----------------
// dt = softplus(dtb @ W_dt^T + b_dt); y = xc * (dt*s + Dskip) * sz  (bf16)
__global__ __launch_bounds__(256)
void gemm_dt_y(const u16* __restrict__ dtb, const u16* __restrict__ Wdt,
               const float* __restrict__ b_dt, const float* __restrict__ Dskip,
               const float* __restrict__ s,
               const u16* __restrict__ xcb, const u16* __restrict__ szb,
               u16* __restrict__ y)
{
    __shared__ u16 Ds[64 * 64];
    __shared__ u16 Ws[128 * 64];
    const int t = threadIdx.x, w = t >> 6, l = t & 63;
    const int wr = w >> 1, wc = w & 1;
    const int brow = blockIdx.y * 64;
    const int bcol = blockIdx.x * 128;
    const int lr = l & 15, l16 = l >> 4;
    const int skk = ((l & 7) ^ (l >> 3)) * 8;

    {
        const u16* Dbase = dtb + (size_t)(brow + (l >> 3)) * 64 + skk;
        const u16* Wbase = Wdt + (size_t)(bcol + (l >> 3)) * 64 + skk;
        #pragma unroll
        for (int c = 0; c < 2; ++c) {
            const int seg = c * 4 + w;
            __builtin_amdgcn_global_load_lds(
                (const __attribute__((address_space(1))) void*)(Dbase + (size_t)seg * 8 * 64),
                (__attribute__((address_space(3))) void*)(&Ds[seg * 512]), 16, 0, 0);
        }
        #pragma unroll
        for (int c = 0; c < 4; ++c) {
            const int seg = c * 4 + w;
            __builtin_amdgcn_global_load_lds(
                (const __attribute__((address_space(1))) void*)(Wbase + (size_t)seg * 8 * 64),
                (__attribute__((address_space(3))) void*)(&Ws[seg * 512]), 16, 0, 0);
        }
    }
    __syncthreads();

    f32x4 acc[2][4] = {};
    #pragma unroll
    for (int kk = 0; kk < 2; ++kk) {
        bf16x8 a[2], b[4];
        #pragma unroll
        for (int m = 0; m < 2; ++m) {
            const int r = wr * 32 + m * 16 + lr;
            a[m] = *(const bf16x8*)(&Ds[r * 64 + (((kk * 4 + l16) ^ (r & 7)) * 8)]);
        }
        #pragma unroll
        for (int n = 0; n < 4; ++n) {
            const int r = wc * 64 + n * 16 + lr;
            b[n] = *(const bf16x8*)(&Ws[r * 64 + (((kk * 4 + l16) ^ (r & 7)) * 8)]);
        }
        #pragma unroll
        for (int m = 0; m < 2; ++m)
            #pragma unroll
            for (int n = 0; n < 4; ++n)
                acc[m][n] = __builtin_amdgcn_mfma_f32_16x16x32_bf16(a[m], b[n], acc[m][n], 0, 0, 0);
    }

    #pragma unroll
    for (int m = 0; m < 2; ++m)
        #pragma unroll
        for (int n = 0; n < 4; ++n)
            #pragma unroll
            for (int r = 0; r < 4; ++r) {
                const int row = brow + wr * 32 + m * 16 + l16 * 4 + r;   // batch idx
                const int col = bcol + wc * 64 + n * 16 + lr;            // d idx
                float v = acc[m][n][r] + b_dt[col];
                float dt = (v > 20.f) ? v : log1pf(__expf(v));
                float xcv = bf2f(xcb[(size_t)row * DINNER + col]);
                float szv = bf2f(szb[(size_t)row * DINNER + col]);
                float yv = (dt * s[row] + Dskip[col]) * xcv * szv;
                y[(size_t)row * DINNER + col] = f2bf(yv);
            }
}

extern "C" void kernel_launch(void* const* d_in, const int* in_sizes, int n_in,
                              void* d_out, int out_size, void* d_ws, size_t ws_size,
                              hipStream_t stream) {
    const float* x      = (const float*)d_in[0];
    const float* ln_g   = (const float*)d_in[1];
    const float* ln_b   = (const float*)d_in[2];
    const float* W_in   = (const float*)d_in[3];
    const float* conv_w = (const float*)d_in[4];
    const float* conv_b = (const float*)d_in[5];
    const float* W_xp   = (const float*)d_in[6];
    const float* W_dt   = (const float*)d_in[7];
    const float* b_dt   = (const float*)d_in[8];
    // d_in[9] = A_log : dead (L=1, h0=0)
    const float* Dskip  = (const float*)d_in[10];
    const float* W_out  = (const float*)d_in[11];
    float* out = (float*)d_out;

    char* ws = (char*)d_ws;
    size_t o = 0;
    auto alloc = [&](size_t bytes) {
        void* p = ws + o;
        o = (o + bytes + 255) & ~(size_t)255;
        return p;
    };
    u16* W_in_b  = (u16*)alloc((size_t)2 * DINNER * DIM * 2);   // 4096x1024
    u16* W_out_b = (u16*)alloc((size_t)DIM * DINNER * 2);       // 1024x2048
    u16* W_xp_b  = (u16*)alloc((size_t)96 * DINNER * 2);        // 96x2048
    u16* W_dt_b  = (u16*)alloc((size_t)DINNER * 64 * 2);        // 2048x64
    u16* xn      = (u16*)alloc((size_t)BATCH * DIM * 2);
    u16* xcb     = (u16*)alloc((size_t)BATCH * DINNER * 2);
    u16* szb     = (u16*)alloc((size_t)BATCH * DINNER * 2);
    float* Pbuf  = (float*)alloc((size_t)4 * 96 * BATCH * 4);   // split-K partials
    u16* dtb     = (u16*)alloc((size_t)BATCH * 64 * 2);
    float* sbuf  = (float*)alloc((size_t)BATCH * 4);
    u16* yb      = (u16*)alloc((size_t)BATCH * DINNER * 2);

    cvt_all<<<2048, 256, 0, stream>>>(
        (const float4*)W_in,  (ushort4*)W_in_b,  (2 * DINNER * DIM) / 4,
        (const float4*)W_out, (ushort4*)W_out_b, (DIM * DINNER) / 4,
        (const float4*)W_xp,  (ushort4*)W_xp_b,  (96 * DINNER) / 4,
        (const float4*)W_dt,  (ushort4*)W_dt_b,  (DINNER * 64) / 4);

    ln_kernel<<<BATCH, 256, 0, stream>>>(x, ln_g, ln_b, xn);

    // GEMM1: xz = xn @ W_in^T  (fused conv+silu epilogue -> xc, sz)
    gemm_bt<1, 128><<<dim3(4096 / 128, BATCH / 128), 256, 0, stream>>>(
        xn, W_in_b, 4096, DIM, nullptr, xcb, szb, conv_w, conv_b);

    // GEMM2 (split-K x4): partials
    gemm_xproj<<<dim3(BATCH / 64, 4), 256, 0, stream>>>(xcb, W_xp_b, Pbuf);

    // finish: dtb bf16 + s[b]
    finish_xdb<<<BATCH / 256, 256, 0, stream>>>(Pbuf, dtb, sbuf);

    // GEMM3 + epilogue: y
    gemm_dt_y<<<dim3(DINNER / 128, BATCH / 64), 256, 0, stream>>>(
        dtb, W_dt_b, b_dt, Dskip, sbuf, xcb, szb, yb);

    // GEMM4: out = y @ W_out^T  (fp32 out, 128x64 tile -> 512 blocks)
    gemm_bt<0, 64><<<dim3(DIM / 64, BATCH / 128), 256, 0, stream>>>(
        yb, W_out_b, DIM, DINNER, out, nullptr, nullptr, nullptr, nullptr);
}

// Round 3
// 161.933 us; speedup vs baseline: 1.2866x; 1.1365x over previous
//
#include <hip/hip_runtime.h>
#include <hip/hip_bf16.h>
#include <stdint.h>

#define DIM     1024
#define DINNER  2048
#define BATCH   4096
#define LN_EPS  1e-5f

typedef unsigned short u16;
using f32x4  = __attribute__((ext_vector_type(4))) float;
using bf16x8 = __attribute__((ext_vector_type(8))) __bf16;

__device__ __forceinline__ float bf2f(u16 h) {
    union { unsigned u; float f; } v; v.u = ((unsigned)h) << 16; return v.f;
}
__device__ __forceinline__ u16 f2bf(float f) {
    union { float f; unsigned u; } v; v.f = f;
    unsigned r = v.u + 0x7fffu + ((v.u >> 16) & 1u);
    return (u16)(r >> 16);
}
__device__ __forceinline__ float silu_f(float x) {
    return x / (1.f + __expf(-x));
}

#define AS1 __attribute__((address_space(1)))
#define AS3 __attribute__((address_space(3)))

// ---------------- fused fp32 -> bf16 weight conversion ----------------
__global__ void cvt_all(const float4* __restrict__ s0, ushort4* __restrict__ d0, int n0,
                        const float4* __restrict__ s1, ushort4* __restrict__ d1, int n1,
                        const float4* __restrict__ s2, ushort4* __restrict__ d2, int n2,
                        const float4* __restrict__ s3, ushort4* __restrict__ d3, int n3) {
    int i = blockIdx.x * blockDim.x + threadIdx.x;
    const int stride = gridDim.x * blockDim.x;
    const int total = n0 + n1 + n2 + n3;
    for (; i < total; i += stride) {
        int j = i; const float4* s; ushort4* d;
        if (j < n0) { s = s0; d = d0; }
        else { j -= n0;
            if (j < n1) { s = s1; d = d1; }
            else { j -= n1;
                if (j < n2) { s = s2; d = d2; }
                else { j -= n2; s = s3; d = d3; }
            }
        }
        float4 v = s[j];
        d[j] = make_ushort4(f2bf(v.x), f2bf(v.y), f2bf(v.z), f2bf(v.w));
    }
}

// ---------------- LayerNorm: x (4096x1024 f32) -> xn (bf16) ----------------
__global__ __launch_bounds__(256)
void ln_kernel(const float* __restrict__ x, const float* __restrict__ gamma,
               const float* __restrict__ beta, u16* __restrict__ xn) {
    const int row = blockIdx.x;
    const int t = threadIdx.x;
    float4 v = ((const float4*)(x + (size_t)row * DIM))[t];
    float s1 = v.x + v.y + v.z + v.w;
    float s2 = v.x*v.x + v.y*v.y + v.z*v.z + v.w*v.w;
    #pragma unroll
    for (int o = 32; o > 0; o >>= 1) {
        s1 += __shfl_down(s1, o);
        s2 += __shfl_down(s2, o);
    }
    __shared__ float red[8];
    __shared__ float mv[2];
    const int w = t >> 6, l = t & 63;
    if (l == 0) { red[w] = s1; red[4 + w] = s2; }
    __syncthreads();
    if (t == 0) {
        float a = red[0] + red[1] + red[2] + red[3];
        float b = red[4] + red[5] + red[6] + red[7];
        float mu = a * (1.f / DIM);
        float var = b * (1.f / DIM) - mu * mu;
        mv[0] = mu; mv[1] = rsqrtf(var + LN_EPS);
    }
    __syncthreads();
    const float mu = mv[0], rs = mv[1];
    float4 g  = ((const float4*)gamma)[t];
    float4 be = ((const float4*)beta)[t];
    ushort4 o = make_ushort4(
        f2bf((v.x - mu) * rs * g.x + be.x),
        f2bf((v.y - mu) * rs * g.y + be.y),
        f2bf((v.z - mu) * rs * g.z + be.z),
        f2bf((v.w - mu) * rs * g.w + be.w));
    *(ushort4*)(xn + (size_t)row * DIM + t * 4) = o;
}

// =============== 256x256 8-phase bt-GEMM (C = A * B^T), bf16, MFMA ===============
// 512 threads = 8 waves (2M x 4N), per-wave output 128x64. BK=64.
// LDS 128KB: lds[buf][slot: Ah0,Ah1,Bh0,Bh1][128*64].
// Swizzle: LDS dest linear (global_load_lds); per-lane GLOBAL source chunk
// pre-swizzled chunk^=(row&7); ds_reads apply same XOR (0 conflicts, R2-verified).
// Phase schedule (derived; reads complete before re-stage via lgkmcnt(0)+barrier;
// counted vmcnt(4) at P4/P8 guarantees landing >= 2 phases before first read):
//   P1: read B(n0-1)+A(m0-3) buf0 | stage (T+1).Ah0->buf1 | MFMA m0-3 x n0-1
//   P2: read B(n2-3) buf0         | stage (T+1).Ah1->buf1 | MFMA m0-3 x n2-3
//   P3: read A(m4-7) buf0         | stage (T+2).Bh0->buf0 | MFMA m4-7 x n0-1
//   P4:                           | stage (T+2).Bh1->buf0 | MFMA m4-7 x n2-3 | vmcnt(4)
//   P5-P8: same with buf0<->buf1, stages (T+2).Ah*->buf0, (T+3).Bh*->buf1
// EPI 1: GEMM1 epilogue (conv tap3 + silu -> xc | silu -> sz)
// EPI 0: fp32 partial write (split-K slice blockIdx.z)
template<int EPI>
__global__ __launch_bounds__(512, 2)
void gemm8(const u16* __restrict__ A, const u16* __restrict__ B,
           int N, int K, int nkt,
           float* __restrict__ outf, u16* __restrict__ xc, u16* __restrict__ sz,
           const float* __restrict__ conv_w, const float* __restrict__ conv_b)
{
    __shared__ __align__(16) u16 lds[2][4][8192];
    const int tid = threadIdx.x;
    const int wid = tid >> 6, l = tid & 63;
    const int wm = wid >> 2, wn = wid & 3;
    const int lr = l & 15, l16 = l >> 4;
    const int brow = blockIdx.y * 256, bcol = blockIdx.x * 256;
    const int kbase = blockIdx.z * nkt * 64;

    // staging source (per-lane pre-swizzled chunk)
    const int sr = tid >> 3;                       // 0..63
    const int skk = ((tid & 7) ^ (sr & 7)) * 8;
    const u16* Ab  = A + (size_t)(brow + sr) * K + kbase + skk;
    const u16* Bb  = B + (size_t)(bcol + sr) * K + kbase + skk;
    const u16* AbH = Ab + (size_t)128 * K;
    const u16* BbH = Bb + (size_t)128 * K;

    // per-thread LDS stage destinations (wave-uniform base + lane*16B)
    u16* const dA0h0 = &lds[0][0][tid * 8]; u16* const dA0h1 = &lds[0][1][tid * 8];
    u16* const dA1h0 = &lds[1][0][tid * 8]; u16* const dA1h1 = &lds[1][1][tid * 8];
    u16* const dB0h0 = &lds[0][2][tid * 8]; u16* const dB0h1 = &lds[0][3][tid * 8];
    u16* const dB1h0 = &lds[1][2][tid * 8]; u16* const dB1h1 = &lds[1][3][tid * 8];

    // read bases
    const u16* const Ar0 = &lds[0][wm][0];
    const u16* const Ar1 = &lds[1][wm][0];
    const u16* const Br0 = &lds[0][2 + (wn >> 1)][((wn & 1) * 64) * 64];
    const u16* const Br1 = &lds[1][2 + (wn >> 1)][((wn & 1) * 64) * 64];

    // read swizzle (lane-const XOR)
    const int cx0 = ((0 + l16) ^ (l & 7)) * 8;
    const int cx1 = ((4 + l16) ^ (l & 7)) * 8;

    f32x4 acc[8][4] = {};
    bf16x8 a[4][2], b0[2][2], b1[2][2];

    auto stage = [&](u16* dst, const u16* srcrow, int kt) {
        const u16* s = srcrow + (size_t)kt * 64;
        __builtin_amdgcn_global_load_lds((const AS1 void*)s, (AS3 void*)dst, 16, 0, 0);
        __builtin_amdgcn_global_load_lds((const AS1 void*)(s + (size_t)64 * K),
                                         (AS3 void*)(dst + 4096), 16, 0, 0);
    };
    auto ldA = [&](const u16* sl, int mb) {
        #pragma unroll
        for (int m = 0; m < 4; ++m) {
            const int r = mb + m * 16 + lr;
            a[m][0] = *(const bf16x8*)(sl + r * 64 + cx0);
            a[m][1] = *(const bf16x8*)(sl + r * 64 + cx1);
        }
    };
    auto ldB = [&](const u16* sl, int nb, bf16x8 (&bf)[2][2]) {
        #pragma unroll
        for (int n = 0; n < 2; ++n) {
            const int r = nb + n * 16 + lr;
            bf[n][0] = *(const bf16x8*)(sl + r * 64 + cx0);
            bf[n][1] = *(const bf16x8*)(sl + r * 64 + cx1);
        }
    };
    auto quad = [&](int mb, bf16x8 (&bf)[2][2], int nb) {
        #pragma unroll
        for (int m = 0; m < 4; ++m)
            #pragma unroll
            for (int n = 0; n < 2; ++n) {
                acc[mb + m][nb + n] = __builtin_amdgcn_mfma_f32_16x16x32_bf16(
                    a[m][0], bf[n][0], acc[mb + m][nb + n], 0, 0, 0);
                acc[mb + m][nb + n] = __builtin_amdgcn_mfma_f32_16x16x32_bf16(
                    a[m][1], bf[n][1], acc[mb + m][nb + n], 0, 0, 0);
            }
    };

#define PH_MID() do { __builtin_amdgcn_s_barrier(); \
    asm volatile("s_waitcnt lgkmcnt(0)" ::: "memory"); \
    __builtin_amdgcn_s_setprio(1); } while (0)
#define PH_END() do { __builtin_amdgcn_s_setprio(0); \
    __builtin_amdgcn_s_barrier(); } while (0)
#define PH_END_VM() do { __builtin_amdgcn_s_setprio(0); \
    asm volatile("s_waitcnt vmcnt(4)" ::: "memory"); \
    __builtin_amdgcn_s_barrier(); } while (0)

    // prologue: tile0 {Bh0,Bh1,Ah0,Ah1}, tile1 {Bh0,Bh1}; vmcnt(4) -> tile0 landed
    stage(dB0h0, Bb, 0);  stage(dB0h1, BbH, 0);
    stage(dA0h0, Ab, 0);  stage(dA0h1, AbH, 0);
    stage(dB1h0, Bb, 1);  stage(dB1h1, BbH, 1);
    asm volatile("s_waitcnt vmcnt(4)" ::: "memory");
    __builtin_amdgcn_s_barrier();

    const int niter = nkt >> 1;
    for (int i = 0; i < niter; ++i) {
        const int T  = 2 * i;
        const int t2 = (T + 2 < nkt) ? T + 2 : nkt - 1;
        const int t3 = (T + 3 < nkt) ? T + 3 : nkt - 1;
        // ---- tile T from buf0 ----
        ldB(Br0, 0, b0); ldA(Ar0, 0);
        stage(dA1h0, Ab, T + 1);
        PH_MID(); quad(0, b0, 0); PH_END();

        ldB(Br0, 32, b1);
        stage(dA1h1, AbH, T + 1);
        PH_MID(); quad(0, b1, 2); PH_END();

        ldA(Ar0, 64);
        stage(dB0h0, Bb, t2);
        PH_MID(); quad(4, b0, 0); PH_END();

        stage(dB0h1, BbH, t2);
        PH_MID(); quad(4, b1, 2); PH_END_VM();

        // ---- tile T+1 from buf1 ----
        ldB(Br1, 0, b0); ldA(Ar1, 0);
        stage(dA0h0, Ab, t2);
        PH_MID(); quad(0, b0, 0); PH_END();

        ldB(Br1, 32, b1);
        stage(dA0h1, AbH, t2);
        PH_MID(); quad(0, b1, 2); PH_END();

        ldA(Ar1, 64);
        stage(dB1h0, Bb, t3);
        PH_MID(); quad(4, b0, 0); PH_END();

        stage(dB1h1, BbH, t3);
        PH_MID(); quad(4, b1, 2); PH_END_VM();
    }
#undef PH_MID
#undef PH_END
#undef PH_END_VM

    // epilogue
    const int r0 = brow + wm * 128;
    const int c0 = bcol + wn * 64;
    if (EPI == 1) {
        if (bcol < DINNER) {
            #pragma unroll
            for (int m = 0; m < 8; ++m)
                #pragma unroll
                for (int n = 0; n < 4; ++n)
                    #pragma unroll
                    for (int r = 0; r < 4; ++r) {
                        const int row = r0 + m * 16 + l16 * 4 + r;
                        const int col = c0 + n * 16 + lr;
                        float v = conv_b[col] + conv_w[col * 4 + 3] * acc[m][n][r];
                        xc[(size_t)row * DINNER + col] = f2bf(silu_f(v));
                    }
        } else {
            #pragma unroll
            for (int m = 0; m < 8; ++m)
                #pragma unroll
                for (int n = 0; n < 4; ++n)
                    #pragma unroll
                    for (int r = 0; r < 4; ++r) {
                        const int row = r0 + m * 16 + l16 * 4 + r;
                        const int col = c0 + n * 16 + lr - DINNER;
                        sz[(size_t)row * DINNER + col] = f2bf(silu_f(acc[m][n][r]));
                    }
        }
    } else {
        float* po = outf + (size_t)blockIdx.z * ((size_t)BATCH * N);
        #pragma unroll
        for (int m = 0; m < 8; ++m)
            #pragma unroll
            for (int n = 0; n < 4; ++n)
                #pragma unroll
                for (int r = 0; r < 4; ++r) {
                    const int row = r0 + m * 16 + l16 * 4 + r;
                    const int col = c0 + n * 16 + lr;
                    po[(size_t)row * N + col] = acc[m][n][r];
                }
    }
}

// ---------------- finish GEMM4: out = sum of 4 split-K partials ----------------
__global__ __launch_bounds__(256)
void finish4(const float4* __restrict__ P, float4* __restrict__ out) {
    const size_t S = (size_t)BATCH * DIM / 4;
    size_t i = (size_t)blockIdx.x * 256 + threadIdx.x;
    const size_t stride = (size_t)gridDim.x * 256;
    for (; i < S; i += stride) {
        float4 v0 = P[i], v1 = P[i + S], v2 = P[i + 2 * S], v3 = P[i + 3 * S];
        out[i] = make_float4(v0.x + v1.x + v2.x + v3.x,
                             v0.y + v1.y + v2.y + v3.y,
                             v0.z + v1.z + v2.z + v3.z,
                             v0.w + v1.w + v2.w + v3.w);
    }
}

// ---------------- GEMM2 split-K: P[ks][96][4096] partials (fp32) ----------------
__global__ __launch_bounds__(256)
void gemm_xproj(const u16* __restrict__ xcb, const u16* __restrict__ Wx,
                float* __restrict__ P)
{
    __shared__ __align__(16) u16 Xs[64 * 64];
    __shared__ __align__(16) u16 Ws[96 * 64];
    const int t = threadIdx.x, w = t >> 6, l = t & 63;
    const int brow = blockIdx.x * 64;
    const int ks = blockIdx.y;
    const int lr = l & 15, l16 = l >> 4;
    const int skk = ((l & 7) ^ (l >> 3)) * 8;
    const u16* Xbase = xcb + (size_t)(brow + (l >> 3)) * DINNER + skk;
    const u16* Wbase = Wx + (size_t)(l >> 3) * DINNER + skk;

    f32x4 acc[6] = {};
    const int kend = ks * 512 + 512;
    for (int k0 = ks * 512; k0 < kend; k0 += 64) {
        #pragma unroll
        for (int c = 0; c < 2; ++c) {
            const int seg = c * 4 + w;
            __builtin_amdgcn_global_load_lds(
                (const AS1 void*)(Xbase + (size_t)seg * 8 * DINNER + k0),
                (AS3 void*)(&Xs[seg * 512]), 16, 0, 0);
        }
        #pragma unroll
        for (int c = 0; c < 3; ++c) {
            const int seg = c * 4 + w;
            __builtin_amdgcn_global_load_lds(
                (const AS1 void*)(Wbase + (size_t)seg * 8 * DINNER + k0),
                (AS3 void*)(&Ws[seg * 512]), 16, 0, 0);
        }
        __syncthreads();
        #pragma unroll
        for (int kk = 0; kk < 2; ++kk) {
            const int ra = w * 16 + lr;
            bf16x8 a = *(const bf16x8*)(&Xs[ra * 64 + (((kk * 4 + l16) ^ (ra & 7)) * 8)]);
            #pragma unroll
            for (int n = 0; n < 6; ++n) {
                const int rb = n * 16 + lr;
                bf16x8 b = *(const bf16x8*)(&Ws[rb * 64 + (((kk * 4 + l16) ^ (rb & 7)) * 8)]);
                acc[n] = __builtin_amdgcn_mfma_f32_16x16x32_bf16(a, b, acc[n], 0, 0, 0);
            }
        }
        __syncthreads();
    }
    #pragma unroll
    for (int n = 0; n < 6; ++n)
        #pragma unroll
        for (int r = 0; r < 4; ++r) {
            const int row = brow + w * 16 + l16 * 4 + r;
            const int col = n * 16 + lr;
            P[((size_t)ks * 96 + col) * BATCH + row] = acc[n][r];
        }
}

// ---------------- finish: sum partials -> dtb (bf16), s[b] ----------------
__global__ __launch_bounds__(256)
void finish_xdb(const float* __restrict__ P, u16* __restrict__ dtb, float* __restrict__ sbuf)
{
    const int b = blockIdx.x * 256 + threadIdx.x;
    #pragma unroll 8
    for (int c = 0; c < 64; ++c) {
        float v = P[((size_t)0 * 96 + c) * BATCH + b] + P[((size_t)1 * 96 + c) * BATCH + b]
                + P[((size_t)2 * 96 + c) * BATCH + b] + P[((size_t)3 * 96 + c) * BATCH + b];
        dtb[(size_t)b * 64 + c] = f2bf(v);
    }
    float s = 0.f;
    for (int n = 0; n < 16; ++n) {
        float Bv = 0.f, Cv = 0.f;
        #pragma unroll
        for (int ks = 0; ks < 4; ++ks) {
            Bv += P[((size_t)ks * 96 + 64 + n) * BATCH + b];
            Cv += P[((size_t)ks * 96 + 80 + n) * BATCH + b];
        }
        s += Bv * Cv;
    }
    sbuf[b] = s;
}

// ---------------- GEMM3 + y epilogue ----------------
__global__ __launch_bounds__(256)
void gemm_dt_y(const u16* __restrict__ dtb, const u16* __restrict__ Wdt,
               const float* __restrict__ b_dt, const float* __restrict__ Dskip,
               const float* __restrict__ s,
               const u16* __restrict__ xcb, const u16* __restrict__ szb,
               u16* __restrict__ y)
{
    __shared__ __align__(16) u16 Ds[64 * 64];
    __shared__ __align__(16) u16 Ws[128 * 64];
    const int t = threadIdx.x, w = t >> 6, l = t & 63;
    const int wr = w >> 1, wc = w & 1;
    const int brow = blockIdx.y * 64;
    const int bcol = blockIdx.x * 128;
    const int lr = l & 15, l16 = l >> 4;
    const int skk = ((l & 7) ^ (l >> 3)) * 8;

    {
        const u16* Dbase = dtb + (size_t)(brow + (l >> 3)) * 64 + skk;
        const u16* Wbase = Wdt + (size_t)(bcol + (l >> 3)) * 64 + skk;
        #pragma unroll
        for (int c = 0; c < 2; ++c) {
            const int seg = c * 4 + w;
            __builtin_amdgcn_global_load_lds(
                (const AS1 void*)(Dbase + (size_t)seg * 8 * 64),
                (AS3 void*)(&Ds[seg * 512]), 16, 0, 0);
        }
        #pragma unroll
        for (int c = 0; c < 4; ++c) {
            const int seg = c * 4 + w;
            __builtin_amdgcn_global_load_lds(
                (const AS1 void*)(Wbase + (size_t)seg * 8 * 64),
                (AS3 void*)(&Ws[seg * 512]), 16, 0, 0);
        }
    }
    __syncthreads();

    f32x4 acc[2][4] = {};
    #pragma unroll
    for (int kk = 0; kk < 2; ++kk) {
        bf16x8 a[2], b[4];
        #pragma unroll
        for (int m = 0; m < 2; ++m) {
            const int r = wr * 32 + m * 16 + lr;
            a[m] = *(const bf16x8*)(&Ds[r * 64 + (((kk * 4 + l16) ^ (r & 7)) * 8)]);
        }
        #pragma unroll
        for (int n = 0; n < 4; ++n) {
            const int r = wc * 64 + n * 16 + lr;
            b[n] = *(const bf16x8*)(&Ws[r * 64 + (((kk * 4 + l16) ^ (r & 7)) * 8)]);
        }
        #pragma unroll
        for (int m = 0; m < 2; ++m)
            #pragma unroll
            for (int n = 0; n < 4; ++n)
                acc[m][n] = __builtin_amdgcn_mfma_f32_16x16x32_bf16(a[m], b[n], acc[m][n], 0, 0, 0);
    }

    #pragma unroll
    for (int m = 0; m < 2; ++m)
        #pragma unroll
        for (int n = 0; n < 4; ++n)
            #pragma unroll
            for (int r = 0; r < 4; ++r) {
                const int row = brow + wr * 32 + m * 16 + l16 * 4 + r;
                const int col = bcol + wc * 64 + n * 16 + lr;
                float v = acc[m][n][r] + b_dt[col];
                float dt = (v > 20.f) ? v : log1pf(__expf(v));
                float xcv = bf2f(xcb[(size_t)row * DINNER + col]);
                float szv = bf2f(szb[(size_t)row * DINNER + col]);
                float yv = (dt * s[row] + Dskip[col]) * xcv * szv;
                y[(size_t)row * DINNER + col] = f2bf(yv);
            }
}

extern "C" void kernel_launch(void* const* d_in, const int* in_sizes, int n_in,
                              void* d_out, int out_size, void* d_ws, size_t ws_size,
                              hipStream_t stream) {
    const float* x      = (const float*)d_in[0];
    const float* ln_g   = (const float*)d_in[1];
    const float* ln_b   = (const float*)d_in[2];
    const float* W_in   = (const float*)d_in[3];
    const float* conv_w = (const float*)d_in[4];
    const float* conv_b = (const float*)d_in[5];
    const float* W_xp   = (const float*)d_in[6];
    const float* W_dt   = (const float*)d_in[7];
    const float* b_dt   = (const float*)d_in[8];
    // d_in[9] = A_log : dead (L=1, h0=0)
    const float* Dskip  = (const float*)d_in[10];
    const float* W_out  = (const float*)d_in[11];
    float* out = (float*)d_out;

    char* ws = (char*)d_ws;
    const size_t MB = 1u << 20;
    // Union region (64MB): GEMM4 partials P4 overlay buffers dead before GEMM4.
    float* P4     = (float*)(ws);                 // 4 x 4096 x 1024 f32 = 64MB
    u16*  W_in_b  = (u16*)(ws);                   // 8MB   [dead after GEMM1]
    u16*  xn      = (u16*)(ws + 8 * MB);          // 8MB   [dead after GEMM1]
    u16*  xcb     = (u16*)(ws + 16 * MB);         // 16MB  [dead after gemm_dt_y]
    u16*  szb     = (u16*)(ws + 32 * MB);         // 16MB  [dead after gemm_dt_y]
    float* Pxp    = (float*)(ws + 48 * MB);       // 6MB   [dead after finish_xdb]
    u16*  W_xp_b  = (u16*)(ws + 55 * MB);         // 384KB [dead after gemm_xproj]
    u16*  W_dt_b  = (u16*)(ws + 56 * MB);         // 256KB [dead after gemm_dt_y]
    u16*  dtb     = (u16*)(ws + 57 * MB);         // 512KB [dead after gemm_dt_y]
    // persistent past 64MB
    u16*  W_out_b = (u16*)(ws + 64 * MB);         // 4MB
    u16*  yb      = (u16*)(ws + 68 * MB);         // 16MB
    float* sbuf   = (float*)(ws + 84 * MB);       // 16KB

    cvt_all<<<2048, 256, 0, stream>>>(
        (const float4*)W_in,  (ushort4*)W_in_b,  (2 * DINNER * DIM) / 4,
        (const float4*)W_out, (ushort4*)W_out_b, (DIM * DINNER) / 4,
        (const float4*)W_xp,  (ushort4*)W_xp_b,  (96 * DINNER) / 4,
        (const float4*)W_dt,  (ushort4*)W_dt_b,  (DINNER * 64) / 4);

    ln_kernel<<<BATCH, 256, 0, stream>>>(x, ln_g, ln_b, xn);

    // GEMM1: xz = xn @ W_in^T (fused conv+silu -> xc, sz). 256 blocks, 8-phase.
    gemm8<1><<<dim3(4096 / 256, BATCH / 256, 1), 512, 0, stream>>>(
        xn, W_in_b, 4096, DIM, DIM / 64, nullptr, xcb, szb, conv_w, conv_b);

    // GEMM2 (split-K x4): partials
    gemm_xproj<<<dim3(BATCH / 64, 4), 256, 0, stream>>>(xcb, W_xp_b, Pxp);

    // finish: dtb bf16 + s[b]
    finish_xdb<<<BATCH / 256, 256, 0, stream>>>(Pxp, dtb, sbuf);

    // GEMM3 + epilogue: y
    gemm_dt_y<<<dim3(DINNER / 128, BATCH / 64), 256, 0, stream>>>(
        dtb, W_dt_b, b_dt, Dskip, sbuf, xcb, szb, yb);

    // GEMM4: out = y @ W_out^T, split-K x4 (256 blocks), fp32 partials
    gemm8<0><<<dim3(DIM / 256, BATCH / 256, 4), 512, 0, stream>>>(
        yb, W_out_b, DIM, DINNER, (DINNER / 4) / 64, P4, nullptr, nullptr, nullptr, nullptr);

    // sum partials -> out
    finish4<<<2048, 256, 0, stream>>>((const float4*)P4, (float4*)out);
}

// Round 4
// 153.942 us; speedup vs baseline: 1.3533x; 1.0519x over previous
//
#include <hip/hip_runtime.h>
#include <hip/hip_bf16.h>
#include <stdint.h>

#define DIM     1024
#define DINNER  2048
#define BATCH   4096
#define LN_EPS  1e-5f

typedef unsigned short u16;
using f32x4  = __attribute__((ext_vector_type(4))) float;
using bf16x8 = __attribute__((ext_vector_type(8))) __bf16;

__device__ __forceinline__ float bf2f(u16 h) {
    union { unsigned u; float f; } v; v.u = ((unsigned)h) << 16; return v.f;
}
__device__ __forceinline__ u16 f2bf(float f) {
    union { float f; unsigned u; } v; v.f = f;
    unsigned r = v.u + 0x7fffu + ((v.u >> 16) & 1u);
    return (u16)(r >> 16);
}
__device__ __forceinline__ float silu_f(float x) {
    return x / (1.f + __expf(-x));
}

#define AS1 __attribute__((address_space(1)))
#define AS3 __attribute__((address_space(3)))

// ---------------- fused weight-cvt + LayerNorm ----------------
// blocks [0, BATCH): LN row; blocks [BATCH, BATCH+2048): grid-stride cvt.
__global__ __launch_bounds__(256)
void cvt_ln(const float* __restrict__ x, const float* __restrict__ gamma,
            const float* __restrict__ beta, u16* __restrict__ xn,
            const float4* __restrict__ s0, ushort4* __restrict__ d0, int n0,
            const float4* __restrict__ s1, ushort4* __restrict__ d1, int n1,
            const float4* __restrict__ s2, ushort4* __restrict__ d2, int n2,
            const float4* __restrict__ s3, ushort4* __restrict__ d3, int n3)
{
    const int t = threadIdx.x;
    if (blockIdx.x < BATCH) {
        const int row = blockIdx.x;
        float4 v = ((const float4*)(x + (size_t)row * DIM))[t];
        float s1v = v.x + v.y + v.z + v.w;
        float s2v = v.x*v.x + v.y*v.y + v.z*v.z + v.w*v.w;
        #pragma unroll
        for (int o = 32; o > 0; o >>= 1) {
            s1v += __shfl_down(s1v, o);
            s2v += __shfl_down(s2v, o);
        }
        __shared__ float red[8];
        __shared__ float mv[2];
        const int w = t >> 6, l = t & 63;
        if (l == 0) { red[w] = s1v; red[4 + w] = s2v; }
        __syncthreads();
        if (t == 0) {
            float a = red[0] + red[1] + red[2] + red[3];
            float b = red[4] + red[5] + red[6] + red[7];
            float mu = a * (1.f / DIM);
            float var = b * (1.f / DIM) - mu * mu;
            mv[0] = mu; mv[1] = rsqrtf(var + LN_EPS);
        }
        __syncthreads();
        const float mu = mv[0], rs = mv[1];
        float4 g  = ((const float4*)gamma)[t];
        float4 be = ((const float4*)beta)[t];
        ushort4 o = make_ushort4(
            f2bf((v.x - mu) * rs * g.x + be.x),
            f2bf((v.y - mu) * rs * g.y + be.y),
            f2bf((v.z - mu) * rs * g.z + be.z),
            f2bf((v.w - mu) * rs * g.w + be.w));
        *(ushort4*)(xn + (size_t)row * DIM + t * 4) = o;
    } else {
        int i = (blockIdx.x - BATCH) * 256 + t;
        const int stride = (gridDim.x - BATCH) * 256;
        const int total = n0 + n1 + n2 + n3;
        for (; i < total; i += stride) {
            int j = i; const float4* s; ushort4* d;
            if (j < n0) { s = s0; d = d0; }
            else { j -= n0;
                if (j < n1) { s = s1; d = d1; }
                else { j -= n1;
                    if (j < n2) { s = s2; d = d2; }
                    else { j -= n2; s = s3; d = d3; }
                }
            }
            float4 v = s[j];
            d[j] = make_ushort4(f2bf(v.x), f2bf(v.y), f2bf(v.z), f2bf(v.w));
        }
    }
}

// =============== 256x256 6-phase bt-GEMM (C = A * B^T), bf16, MFMA ===============
// 512 threads = 8 waves (2M x 4N), per-wave 128x64. BK=64, 2 K-tiles/iter.
// LDS 128KB dbuf; XOR swizzle both-sides (rule 21), zero conflicts (R2-verified).
// 6 phases/iter: F1{12 rd, stage Ah0(T+1), 16 MFMA} F2{4 rd, Ah1(T+1), 16}
//   F3{8 rd, Bh0+Bh1(T+2), 32 MFMA, vmcnt(4)} F4-F6 same for tile T+1.
// vmcnt ledger: F3-end outstanding = B(T+1)4 + A(T+1)4 + B(T+2)4 -> vmcnt(4)
//   guarantees tile T+1; F6-end = A(T+2)4 + B(T+3)4 -> guarantees A(T+2).
// Tail: clamped dummy re-stages keep counts invariant (L2-hot).
// Epilogue: vmcnt(0) drain, LDS bounce (256x256 u16 = 128KB), coalesced 16B stores.
// EPI 1: GEMM1 (conv tap3+silu -> xc | silu -> sz). EPI 2: bf16 partial (split-K z).
template<int EPI>
__global__ __launch_bounds__(512, 2)
void gemm8(const u16* __restrict__ A, const u16* __restrict__ B,
           int N, int K, int nkt,
           u16* __restrict__ dst0, u16* __restrict__ dst1,
           const float* __restrict__ conv_w, const float* __restrict__ conv_b)
{
    __shared__ __align__(16) u16 lds[2][4][8192];
    const int tid = threadIdx.x;
    const int wid = tid >> 6, l = tid & 63;
    const int wm = wid >> 2, wn = wid & 3;
    const int lr = l & 15, l16 = l >> 4;
    const int brow = blockIdx.y * 256, bcol = blockIdx.x * 256;
    const int kbase = blockIdx.z * nkt * 64;

    const int sr = tid >> 3;
    const int skk = ((tid & 7) ^ (sr & 7)) * 8;
    const u16* Ab  = A + (size_t)(brow + sr) * K + kbase + skk;
    const u16* Bb  = B + (size_t)(bcol + sr) * K + kbase + skk;
    const u16* AbH = Ab + (size_t)128 * K;
    const u16* BbH = Bb + (size_t)128 * K;

    u16* const dA0h0 = &lds[0][0][tid * 8]; u16* const dA0h1 = &lds[0][1][tid * 8];
    u16* const dA1h0 = &lds[1][0][tid * 8]; u16* const dA1h1 = &lds[1][1][tid * 8];
    u16* const dB0h0 = &lds[0][2][tid * 8]; u16* const dB0h1 = &lds[0][3][tid * 8];
    u16* const dB1h0 = &lds[1][2][tid * 8]; u16* const dB1h1 = &lds[1][3][tid * 8];

    const u16* const Ar0 = &lds[0][wm][0];
    const u16* const Ar1 = &lds[1][wm][0];
    const u16* const Br0 = &lds[0][2 + (wn >> 1)][((wn & 1) * 64) * 64];
    const u16* const Br1 = &lds[1][2 + (wn >> 1)][((wn & 1) * 64) * 64];

    const int cx0 = ((0 + l16) ^ (l & 7)) * 8;
    const int cx1 = ((4 + l16) ^ (l & 7)) * 8;

    f32x4 acc[8][4] = {};
    bf16x8 a[4][2], b0[2][2], b1[2][2];

    auto stage = [&](u16* dst, const u16* srcrow, int kt) {
        const u16* s = srcrow + (size_t)kt * 64;
        __builtin_amdgcn_global_load_lds((const AS1 void*)s, (AS3 void*)dst, 16, 0, 0);
        __builtin_amdgcn_global_load_lds((const AS1 void*)(s + (size_t)64 * K),
                                         (AS3 void*)(dst + 4096), 16, 0, 0);
    };
    auto ldA = [&](const u16* sl, int mb) {
        #pragma unroll
        for (int m = 0; m < 4; ++m) {
            const int r = mb + m * 16 + lr;
            a[m][0] = *(const bf16x8*)(sl + r * 64 + cx0);
            a[m][1] = *(const bf16x8*)(sl + r * 64 + cx1);
        }
    };
    auto ldB = [&](const u16* sl, int nb, bf16x8 (&bf)[2][2]) {
        #pragma unroll
        for (int n = 0; n < 2; ++n) {
            const int r = nb + n * 16 + lr;
            bf[n][0] = *(const bf16x8*)(sl + r * 64 + cx0);
            bf[n][1] = *(const bf16x8*)(sl + r * 64 + cx1);
        }
    };
    auto quad = [&](int mb, bf16x8 (&bf)[2][2], int nb) {
        #pragma unroll
        for (int m = 0; m < 4; ++m)
            #pragma unroll
            for (int n = 0; n < 2; ++n) {
                acc[mb + m][nb + n] = __builtin_amdgcn_mfma_f32_16x16x32_bf16(
                    a[m][0], bf[n][0], acc[mb + m][nb + n], 0, 0, 0);
                acc[mb + m][nb + n] = __builtin_amdgcn_mfma_f32_16x16x32_bf16(
                    a[m][1], bf[n][1], acc[mb + m][nb + n], 0, 0, 0);
            }
    };

#define PH_MID() do { __builtin_amdgcn_s_barrier(); \
    asm volatile("s_waitcnt lgkmcnt(0)" ::: "memory"); \
    __builtin_amdgcn_sched_barrier(0); \
    __builtin_amdgcn_s_setprio(1); } while (0)
#define PH_END() do { __builtin_amdgcn_s_setprio(0); \
    __builtin_amdgcn_s_barrier(); } while (0)
#define PH_END_VM() do { __builtin_amdgcn_s_setprio(0); \
    asm volatile("s_waitcnt vmcnt(4)" ::: "memory"); \
    __builtin_amdgcn_s_barrier(); } while (0)

    // prologue: [B(0):4][A(0):4][B(1):4]; vmcnt(4) -> tile0 landed
    stage(dB0h0, Bb, 0);  stage(dB0h1, BbH, 0);
    stage(dA0h0, Ab, 0);  stage(dA0h1, AbH, 0);
    stage(dB1h0, Bb, (1 < nkt) ? 1 : 0);  stage(dB1h1, BbH, (1 < nkt) ? 1 : 0);
    asm volatile("s_waitcnt vmcnt(4)" ::: "memory");
    __builtin_amdgcn_s_barrier();

    const int niter = nkt >> 1;
    for (int i = 0; i < niter; ++i) {
        const int T  = 2 * i;
        const int t2 = (T + 2 < nkt) ? T + 2 : nkt - 1;
        const int t3 = (T + 3 < nkt) ? T + 3 : nkt - 1;
        // ---- tile T (buf0) ----
        ldB(Br0, 0, b0); ldA(Ar0, 0);
        stage(dA1h0, Ab, T + 1);
        PH_MID(); quad(0, b0, 0); PH_END();

        ldB(Br0, 32, b1);
        stage(dA1h1, AbH, T + 1);
        PH_MID(); quad(0, b1, 2); PH_END();

        ldA(Ar0, 64);
        stage(dB0h0, Bb, t2); stage(dB0h1, BbH, t2);
        PH_MID(); quad(4, b0, 0); quad(4, b1, 2); PH_END_VM();

        // ---- tile T+1 (buf1) ----
        ldB(Br1, 0, b0); ldA(Ar1, 0);
        stage(dA0h0, Ab, t2);
        PH_MID(); quad(0, b0, 0); PH_END();

        ldB(Br1, 32, b1);
        stage(dA0h1, AbH, t2);
        PH_MID(); quad(0, b1, 2); PH_END();

        ldA(Ar1, 64);
        stage(dB1h0, Bb, t3); stage(dB1h1, BbH, t3);
        PH_MID(); quad(4, b0, 0); quad(4, b1, 2); PH_END_VM();
    }
#undef PH_MID
#undef PH_END
#undef PH_END_VM

    // ---- epilogue: drain DMA, LDS bounce, coalesced stores ----
    asm volatile("s_waitcnt vmcnt(0)" ::: "memory");
    __builtin_amdgcn_s_barrier();

    float cb[4], cw[4];
    const bool isxc = (EPI == 1) && (bcol < DINNER);
    if (isxc) {
        #pragma unroll
        for (int n = 0; n < 4; ++n) {
            const int cg = bcol + wn * 64 + n * 16 + lr;
            cb[n] = conv_b[cg]; cw[n] = conv_w[cg * 4 + 3];
        }
    }
    u16* eb = &lds[0][0][0];   // 256x256 u16 = 128KB
    #pragma unroll
    for (int m = 0; m < 8; ++m)
        #pragma unroll
        for (int n = 0; n < 4; ++n)
            #pragma unroll
            for (int r = 0; r < 4; ++r) {
                const int rl = wm * 128 + m * 16 + l16 * 4 + r;
                const int cl = wn * 64 + n * 16 + lr;
                float v = acc[m][n][r];
                if (EPI == 1) v = isxc ? silu_f(cb[n] + cw[n] * v) : silu_f(v);
                eb[rl * 256 + cl] = f2bf(v);
            }
    __syncthreads();

    if (EPI == 1) {
        u16* base = isxc ? (dst0 + bcol) : (dst1 + (bcol - DINNER));
        #pragma unroll
        for (int it = 0; it < 16; ++it) {
            const int idx = it * 4096 + tid * 8;
            const int r = idx >> 8, c = idx & 255;
            *(uint4*)(base + (size_t)(brow + r) * DINNER + c) = *(const uint4*)(eb + idx);
        }
    } else {
        u16* base = dst0 + ((size_t)blockIdx.z * BATCH) * N + bcol;
        #pragma unroll
        for (int it = 0; it < 16; ++it) {
            const int idx = it * 4096 + tid * 8;
            const int r = idx >> 8, c = idx & 255;
            *(uint4*)(base + (size_t)(brow + r) * N + c) = *(const uint4*)(eb + idx);
        }
    }
}

// ---------------- finish GEMM4: out = sum of 4 bf16 split-K partials ----------------
__global__ __launch_bounds__(256)
void finish4b(const u16* __restrict__ P, float* __restrict__ out) {
    const size_t S = (size_t)BATCH * DIM;
    size_t i8 = ((size_t)blockIdx.x * 256 + threadIdx.x) * 8;
    const size_t stride = (size_t)gridDim.x * 256 * 8;
    for (; i8 < S; i8 += stride) {
        uint4 p0 = *(const uint4*)(P + i8);
        uint4 p1 = *(const uint4*)(P + S + i8);
        uint4 p2 = *(const uint4*)(P + 2 * S + i8);
        uint4 p3 = *(const uint4*)(P + 3 * S + i8);
        float o[8];
        #pragma unroll
        for (int k = 0; k < 4; ++k) {
            unsigned a0 = ((const unsigned*)&p0)[k], a1 = ((const unsigned*)&p1)[k];
            unsigned a2 = ((const unsigned*)&p2)[k], a3 = ((const unsigned*)&p3)[k];
            o[2*k]   = bf2f((u16)a0) + bf2f((u16)a1) + bf2f((u16)a2) + bf2f((u16)a3);
            o[2*k+1] = bf2f((u16)(a0>>16)) + bf2f((u16)(a1>>16)) + bf2f((u16)(a2>>16)) + bf2f((u16)(a3>>16));
        }
        *(float4*)(out + i8)     = make_float4(o[0], o[1], o[2], o[3]);
        *(float4*)(out + i8 + 4) = make_float4(o[4], o[5], o[6], o[7]);
    }
}

// ---------------- GEMM2 split-K: P[ks][96][4096] partials (fp32) ----------------
__global__ __launch_bounds__(256)
void gemm_xproj(const u16* __restrict__ xcb, const u16* __restrict__ Wx,
                float* __restrict__ P)
{
    __shared__ __align__(16) u16 Xs[64 * 64];
    __shared__ __align__(16) u16 Ws[96 * 64];
    const int t = threadIdx.x, w = t >> 6, l = t & 63;
    const int brow = blockIdx.x * 64;
    const int ks = blockIdx.y;
    const int lr = l & 15, l16 = l >> 4;
    const int skk = ((l & 7) ^ (l >> 3)) * 8;
    const u16* Xbase = xcb + (size_t)(brow + (l >> 3)) * DINNER + skk;
    const u16* Wbase = Wx + (size_t)(l >> 3) * DINNER + skk;

    f32x4 acc[6] = {};
    const int kend = ks * 512 + 512;
    for (int k0 = ks * 512; k0 < kend; k0 += 64) {
        #pragma unroll
        for (int c = 0; c < 2; ++c) {
            const int seg = c * 4 + w;
            __builtin_amdgcn_global_load_lds(
                (const AS1 void*)(Xbase + (size_t)seg * 8 * DINNER + k0),
                (AS3 void*)(&Xs[seg * 512]), 16, 0, 0);
        }
        #pragma unroll
        for (int c = 0; c < 3; ++c) {
            const int seg = c * 4 + w;
            __builtin_amdgcn_global_load_lds(
                (const AS1 void*)(Wbase + (size_t)seg * 8 * DINNER + k0),
                (AS3 void*)(&Ws[seg * 512]), 16, 0, 0);
        }
        __syncthreads();
        #pragma unroll
        for (int kk = 0; kk < 2; ++kk) {
            const int ra = w * 16 + lr;
            bf16x8 av = *(const bf16x8*)(&Xs[ra * 64 + (((kk * 4 + l16) ^ (ra & 7)) * 8)]);
            #pragma unroll
            for (int n = 0; n < 6; ++n) {
                const int rb = n * 16 + lr;
                bf16x8 bv = *(const bf16x8*)(&Ws[rb * 64 + (((kk * 4 + l16) ^ (rb & 7)) * 8)]);
                acc[n] = __builtin_amdgcn_mfma_f32_16x16x32_bf16(av, bv, acc[n], 0, 0, 0);
            }
        }
        __syncthreads();
    }
    #pragma unroll
    for (int n = 0; n < 6; ++n)
        #pragma unroll
        for (int r = 0; r < 4; ++r) {
            const int row = brow + w * 16 + l16 * 4 + r;
            const int col = n * 16 + lr;
            P[((size_t)ks * 96 + col) * BATCH + row] = acc[n][r];
        }
}

// ---------------- finish: sum partials -> dtb (bf16), s[b] ----------------
__global__ __launch_bounds__(256)
void finish_xdb(const float* __restrict__ P, u16* __restrict__ dtb, float* __restrict__ sbuf)
{
    const int b = blockIdx.x * 256 + threadIdx.x;
    #pragma unroll 8
    for (int c = 0; c < 64; ++c) {
        float v = P[((size_t)0 * 96 + c) * BATCH + b] + P[((size_t)1 * 96 + c) * BATCH + b]
                + P[((size_t)2 * 96 + c) * BATCH + b] + P[((size_t)3 * 96 + c) * BATCH + b];
        dtb[(size_t)b * 64 + c] = f2bf(v);
    }
    float s = 0.f;
    for (int n = 0; n < 16; ++n) {
        float Bv = 0.f, Cv = 0.f;
        #pragma unroll
        for (int ks = 0; ks < 4; ++ks) {
            Bv += P[((size_t)ks * 96 + 64 + n) * BATCH + b];
            Cv += P[((size_t)ks * 96 + 80 + n) * BATCH + b];
        }
        s += Bv * Cv;
    }
    sbuf[b] = s;
}

// ---------------- GEMM3 + y epilogue ----------------
__global__ __launch_bounds__(256)
void gemm_dt_y(const u16* __restrict__ dtb, const u16* __restrict__ Wdt,
               const float* __restrict__ b_dt, const float* __restrict__ Dskip,
               const float* __restrict__ s,
               const u16* __restrict__ xcb, const u16* __restrict__ szb,
               u16* __restrict__ y)
{
    __shared__ __align__(16) u16 Ds[64 * 64];
    __shared__ __align__(16) u16 Ws[128 * 64];
    const int t = threadIdx.x, w = t >> 6, l = t & 63;
    const int wr = w >> 1, wc = w & 1;
    const int brow = blockIdx.y * 64;
    const int bcol = blockIdx.x * 128;
    const int lr = l & 15, l16 = l >> 4;
    const int skk = ((l & 7) ^ (l >> 3)) * 8;

    {
        const u16* Dbase = dtb + (size_t)(brow + (l >> 3)) * 64 + skk;
        const u16* Wbase = Wdt + (size_t)(bcol + (l >> 3)) * 64 + skk;
        #pragma unroll
        for (int c = 0; c < 2; ++c) {
            const int seg = c * 4 + w;
            __builtin_amdgcn_global_load_lds(
                (const AS1 void*)(Dbase + (size_t)seg * 8 * 64),
                (AS3 void*)(&Ds[seg * 512]), 16, 0, 0);
        }
        #pragma unroll
        for (int c = 0; c < 4; ++c) {
            const int seg = c * 4 + w;
            __builtin_amdgcn_global_load_lds(
                (const AS1 void*)(Wbase + (size_t)seg * 8 * 64),
                (AS3 void*)(&Ws[seg * 512]), 16, 0, 0);
        }
    }
    __syncthreads();

    f32x4 acc[2][4] = {};
    #pragma unroll
    for (int kk = 0; kk < 2; ++kk) {
        bf16x8 av[2], bv[4];
        #pragma unroll
        for (int m = 0; m < 2; ++m) {
            const int r = wr * 32 + m * 16 + lr;
            av[m] = *(const bf16x8*)(&Ds[r * 64 + (((kk * 4 + l16) ^ (r & 7)) * 8)]);
        }
        #pragma unroll
        for (int n = 0; n < 4; ++n) {
            const int r = wc * 64 + n * 16 + lr;
            bv[n] = *(const bf16x8*)(&Ws[r * 64 + (((kk * 4 + l16) ^ (r & 7)) * 8)]);
        }
        #pragma unroll
        for (int m = 0; m < 2; ++m)
            #pragma unroll
            for (int n = 0; n < 4; ++n)
                acc[m][n] = __builtin_amdgcn_mfma_f32_16x16x32_bf16(av[m], bv[n], acc[m][n], 0, 0, 0);
    }

    #pragma unroll
    for (int m = 0; m < 2; ++m)
        #pragma unroll
        for (int n = 0; n < 4; ++n)
            #pragma unroll
            for (int r = 0; r < 4; ++r) {
                const int row = brow + wr * 32 + m * 16 + l16 * 4 + r;
                const int col = bcol + wc * 64 + n * 16 + lr;
                float v = acc[m][n][r] + b_dt[col];
                float dt = (v > 20.f) ? v : log1pf(__expf(v));
                float xcv = bf2f(xcb[(size_t)row * DINNER + col]);
                float szv = bf2f(szb[(size_t)row * DINNER + col]);
                float yv = (dt * s[row] + Dskip[col]) * xcv * szv;
                y[(size_t)row * DINNER + col] = f2bf(yv);
            }
}

extern "C" void kernel_launch(void* const* d_in, const int* in_sizes, int n_in,
                              void* d_out, int out_size, void* d_ws, size_t ws_size,
                              hipStream_t stream) {
    const float* x      = (const float*)d_in[0];
    const float* ln_g   = (const float*)d_in[1];
    const float* ln_b   = (const float*)d_in[2];
    const float* W_in   = (const float*)d_in[3];
    const float* conv_w = (const float*)d_in[4];
    const float* conv_b = (const float*)d_in[5];
    const float* W_xp   = (const float*)d_in[6];
    const float* W_dt   = (const float*)d_in[7];
    const float* b_dt   = (const float*)d_in[8];
    // d_in[9] = A_log : dead (L=1, h0=0)
    const float* Dskip  = (const float*)d_in[10];
    const float* W_out  = (const float*)d_in[11];
    float* out = (float*)d_out;

    char* ws = (char*)d_ws;
    const size_t MB = 1u << 20;
    // Overlay: P4b (32MB bf16 partials) reuses [0,32MB) = W_in_b+xn+xcb (dead by GEMM4).
    u16*  P4b     = (u16*)(ws);                   // 4 x 4096 x 1024 bf16 = 32MB
    u16*  W_in_b  = (u16*)(ws);                   // 8MB   [dead after GEMM1]
    u16*  xn      = (u16*)(ws + 8 * MB);          // 8MB   [dead after GEMM1]
    u16*  xcb     = (u16*)(ws + 16 * MB);         // 16MB  [dead after gemm_dt_y]
    u16*  szb     = (u16*)(ws + 32 * MB);         // 16MB  [dead after gemm_dt_y]
    float* Pxp    = (float*)(ws + 48 * MB);       // 6MB   [dead after finish_xdb]
    u16*  W_xp_b  = (u16*)(ws + 55 * MB);         // 384KB
    u16*  W_dt_b  = (u16*)(ws + 56 * MB);         // 256KB
    u16*  dtb     = (u16*)(ws + 57 * MB);         // 512KB
    u16*  W_out_b = (u16*)(ws + 64 * MB);         // 4MB
    u16*  yb      = (u16*)(ws + 68 * MB);         // 16MB
    float* sbuf   = (float*)(ws + 84 * MB);       // 16KB

    // fused cvt + LN
    cvt_ln<<<BATCH + 2048, 256, 0, stream>>>(
        x, ln_g, ln_b, xn,
        (const float4*)W_in,  (ushort4*)W_in_b,  (2 * DINNER * DIM) / 4,
        (const float4*)W_out, (ushort4*)W_out_b, (DIM * DINNER) / 4,
        (const float4*)W_xp,  (ushort4*)W_xp_b,  (96 * DINNER) / 4,
        (const float4*)W_dt,  (ushort4*)W_dt_b,  (DINNER * 64) / 4);

    // GEMM1: xz = xn @ W_in^T (fused conv+silu -> xc, sz). 256 blocks, 6-phase.
    gemm8<1><<<dim3(4096 / 256, BATCH / 256, 1), 512, 0, stream>>>(
        xn, W_in_b, 4096, DIM, DIM / 64, xcb, szb, conv_w, conv_b);

    // GEMM2 (split-K x4): partials
    gemm_xproj<<<dim3(BATCH / 64, 4), 256, 0, stream>>>(xcb, W_xp_b, Pxp);

    // finish: dtb bf16 + s[b]
    finish_xdb<<<BATCH / 256, 256, 0, stream>>>(Pxp, dtb, sbuf);

    // GEMM3 + epilogue: y
    gemm_dt_y<<<dim3(DINNER / 128, BATCH / 64), 256, 0, stream>>>(
        dtb, W_dt_b, b_dt, Dskip, sbuf, xcb, szb, yb);

    // GEMM4: out = y @ W_out^T, split-K x4, bf16 partials
    gemm8<2><<<dim3(DIM / 256, BATCH / 256, 4), 512, 0, stream>>>(
        yb, W_out_b, DIM, DINNER, (DINNER / 4) / 64, P4b, nullptr, nullptr, nullptr);

    // sum bf16 partials -> fp32 out
    finish4b<<<2048, 256, 0, stream>>>(P4b, out);
}

// Round 5
// 153.407 us; speedup vs baseline: 1.3581x; 1.0035x over previous
//
#include <hip/hip_runtime.h>
#include <hip/hip_bf16.h>
#include <stdint.h>

#define DIM     1024
#define DINNER  2048
#define BATCH   4096
#define LN_EPS  1e-5f

typedef unsigned short u16;
using f32x4  = __attribute__((ext_vector_type(4))) float;
using bf16x8 = __attribute__((ext_vector_type(8))) __bf16;

__device__ __forceinline__ float bf2f(u16 h) {
    union { unsigned u; float f; } v; v.u = ((unsigned)h) << 16; return v.f;
}
__device__ __forceinline__ u16 f2bf(float f) {
    union { float f; unsigned u; } v; v.f = f;
    unsigned r = v.u + 0x7fffu + ((v.u >> 16) & 1u);
    return (u16)(r >> 16);
}
__device__ __forceinline__ float silu_f(float x) {
    return x / (1.f + __expf(-x));
}

#define AS1 __attribute__((address_space(1)))
#define AS3 __attribute__((address_space(3)))

__device__ __forceinline__ unsigned lds_u32(const void* p) {
    return (unsigned)(unsigned long long)(const AS3 void*)p;
}

// ---------------- fused weight-cvt + LayerNorm ----------------
__global__ __launch_bounds__(256)
void cvt_ln(const float* __restrict__ x, const float* __restrict__ gamma,
            const float* __restrict__ beta, u16* __restrict__ xn,
            const float4* __restrict__ s0, ushort4* __restrict__ d0, int n0,
            const float4* __restrict__ s1, ushort4* __restrict__ d1, int n1,
            const float4* __restrict__ s2, ushort4* __restrict__ d2, int n2,
            const float4* __restrict__ s3, ushort4* __restrict__ d3, int n3)
{
    const int t = threadIdx.x;
    if (blockIdx.x < BATCH) {
        const int row = blockIdx.x;
        float4 v = ((const float4*)(x + (size_t)row * DIM))[t];
        float s1v = v.x + v.y + v.z + v.w;
        float s2v = v.x*v.x + v.y*v.y + v.z*v.z + v.w*v.w;
        #pragma unroll
        for (int o = 32; o > 0; o >>= 1) {
            s1v += __shfl_down(s1v, o);
            s2v += __shfl_down(s2v, o);
        }
        __shared__ float red[8];
        __shared__ float mv[2];
        const int w = t >> 6, l = t & 63;
        if (l == 0) { red[w] = s1v; red[4 + w] = s2v; }
        __syncthreads();
        if (t == 0) {
            float a = red[0] + red[1] + red[2] + red[3];
            float b = red[4] + red[5] + red[6] + red[7];
            float mu = a * (1.f / DIM);
            float var = b * (1.f / DIM) - mu * mu;
            mv[0] = mu; mv[1] = rsqrtf(var + LN_EPS);
        }
        __syncthreads();
        const float mu = mv[0], rs = mv[1];
        float4 g  = ((const float4*)gamma)[t];
        float4 be = ((const float4*)beta)[t];
        ushort4 o = make_ushort4(
            f2bf((v.x - mu) * rs * g.x + be.x),
            f2bf((v.y - mu) * rs * g.y + be.y),
            f2bf((v.z - mu) * rs * g.z + be.z),
            f2bf((v.w - mu) * rs * g.w + be.w));
        *(ushort4*)(xn + (size_t)row * DIM + t * 4) = o;
    } else {
        int i = (blockIdx.x - BATCH) * 256 + t;
        const int stride = (gridDim.x - BATCH) * 256;
        const int total = n0 + n1 + n2 + n3;
        for (; i < total; i += stride) {
            int j = i; const float4* s; ushort4* d;
            if (j < n0) { s = s0; d = d0; }
            else { j -= n0;
                if (j < n1) { s = s1; d = d1; }
                else { j -= n1;
                    if (j < n2) { s = s2; d = d2; }
                    else { j -= n2; s = s3; d = d3; }
                }
            }
            float4 v = s[j];
            d[j] = make_ushort4(f2bf(v.x), f2bf(v.y), f2bf(v.z), f2bf(v.w));
        }
    }
}

// =============== 256x256 pipelined bt-GEMM (C = A * B^T), bf16, MFMA ===============
// 512 threads = 8 waves (2M x 4N), per-wave 128x64. BK=64, 1 barrier per K-tile.
// Fragment loads via inline-asm ds_read_b128 (counted lgkmcnt, rule-18 fences).
// Per tile: [rd aHi][lgkm(8)][32 MFMA lo][lgkm(0)][vmcnt(0)][barrier]
//           [stage T+2 -> cur buf][16 MFMA hi0][rd bC0',aLo'][16 MFMA hi1][rd bC1']
// Ledger: lgkm enters 16 (bC+aLo of this tile, issued end of prev tile);
//         vm enters 8 (next tile's staging, issued one tile earlier).
// XOR swizzle both-sides (rule 21): LDS linear dest, pre-swizzled global src,
// swizzled asm-read addresses (0 conflicts, R2-verified).
#define DSR(d, adr, OFFSTR) \
    asm volatile("ds_read_b128 %0, %1 offset:" OFFSTR : "=v"(d) : "v"(adr))
#define RD_A8(DST, A0, A1, S0, S1, S2, S3) do { \
    DSR(DST[0][0], A0, S0); DSR(DST[0][1], A1, S0); \
    DSR(DST[1][0], A0, S1); DSR(DST[1][1], A1, S1); \
    DSR(DST[2][0], A0, S2); DSR(DST[2][1], A1, S2); \
    DSR(DST[3][0], A0, S3); DSR(DST[3][1], A1, S3); } while (0)
#define RD_B4(DST, A0, A1, S0, S1) do { \
    DSR(DST[0][0], A0, S0); DSR(DST[0][1], A1, S0); \
    DSR(DST[1][0], A0, S1); DSR(DST[1][1], A1, S1); } while (0)

#define BC8(x) __builtin_bit_cast(bf16x8, x)
#define MF1(C, Av, Bv) C = __builtin_amdgcn_mfma_f32_16x16x32_bf16(BC8(Av), BC8(Bv), C, 0, 0, 0)

#define CL32_LO do { \
    _Pragma("unroll") for (int m = 0; m < 4; ++m) \
    _Pragma("unroll") for (int n = 0; n < 2; ++n) \
    _Pragma("unroll") for (int k = 0; k < 2; ++k) { \
        MF1(acc[m][n],     aLo[m][k], bC0[n][k]); \
        MF1(acc[m][n + 2], aLo[m][k], bC1[n][k]); } } while (0)
#define CL16_HI0 do { \
    _Pragma("unroll") for (int m = 0; m < 4; ++m) \
    _Pragma("unroll") for (int n = 0; n < 2; ++n) \
    _Pragma("unroll") for (int k = 0; k < 2; ++k) \
        MF1(acc[4 + m][n], aHi[m][k], bC0[n][k]); } while (0)
#define CL16_HI1 do { \
    _Pragma("unroll") for (int m = 0; m < 4; ++m) \
    _Pragma("unroll") for (int n = 0; n < 2; ++n) \
    _Pragma("unroll") for (int k = 0; k < 2; ++k) \
        MF1(acc[4 + m][n + 2], aHi[m][k], bC1[n][k]); } while (0)

#define WAIT_LGKM8 do { asm volatile("s_waitcnt lgkmcnt(8)" ::: "memory"); \
    __builtin_amdgcn_sched_barrier(0); } while (0)
#define WAIT_LGKM0 do { asm volatile("s_waitcnt lgkmcnt(0)" ::: "memory"); \
    __builtin_amdgcn_sched_barrier(0); } while (0)

#define TILE_BODY(CA0, CA1, NA0, NA1, NB0, NB1, SDA0, SDA1, SDB0, SDB1, KT) do { \
    RD_A8(aHi, CA0, CA1, "8192", "10240", "12288", "14336"); \
    WAIT_LGKM8; \
    __builtin_amdgcn_s_setprio(1); CL32_LO; __builtin_amdgcn_s_setprio(0); \
    WAIT_LGKM0; \
    asm volatile("s_waitcnt vmcnt(0)" ::: "memory"); \
    __builtin_amdgcn_s_barrier(); \
    stage(SDB0, Bb, KT); stage(SDB1, BbH, KT); \
    stage(SDA0, Ab, KT); stage(SDA1, AbH, KT); \
    __builtin_amdgcn_s_setprio(1); CL16_HI0; __builtin_amdgcn_s_setprio(0); \
    RD_B4(bC0, NB0, NB1, "0", "2048"); \
    RD_A8(aLo, NA0, NA1, "0", "2048", "4096", "6144"); \
    __builtin_amdgcn_s_setprio(1); CL16_HI1; __builtin_amdgcn_s_setprio(0); \
    RD_B4(bC1, NB0, NB1, "4096", "6144"); \
} while (0)

template<int EPI>
__global__ __launch_bounds__(512, 2)
void gemmP(const u16* __restrict__ A, const u16* __restrict__ B,
           int N, int K, int nkt,
           u16* __restrict__ dst0, u16* __restrict__ dst1,
           const float* __restrict__ conv_w, const float* __restrict__ conv_b)
{
    __shared__ __align__(16) u16 lds[2][4][8192];
    const int tid = threadIdx.x;
    const int wid = tid >> 6, l = tid & 63;
    const int wm = wid >> 2, wn = wid & 3;
    const int lr = l & 15, l16 = l >> 4;
    const int brow = blockIdx.y * 256, bcol = blockIdx.x * 256;
    const int kbase = blockIdx.z * nkt * 64;

    // staging source (per-lane pre-swizzled chunk)
    const int sr = tid >> 3;
    const int skk = ((tid & 7) ^ (sr & 7)) * 8;
    const u16* Ab  = A + (size_t)(brow + sr) * K + kbase + skk;
    const u16* Bb  = B + (size_t)(bcol + sr) * K + kbase + skk;
    const u16* AbH = Ab + (size_t)128 * K;
    const u16* BbH = Bb + (size_t)128 * K;

    // per-thread LDS stage destinations (wave-uniform base + lane*16B)
    u16* const dA0h0 = &lds[0][0][tid * 8]; u16* const dA0h1 = &lds[0][1][tid * 8];
    u16* const dA1h0 = &lds[1][0][tid * 8]; u16* const dA1h1 = &lds[1][1][tid * 8];
    u16* const dB0h0 = &lds[0][2][tid * 8]; u16* const dB0h1 = &lds[0][3][tid * 8];
    u16* const dB1h0 = &lds[1][2][tid * 8]; u16* const dB1h1 = &lds[1][3][tid * 8];

    // fragment read addresses (byte, swizzled, lane-const XOR)
    const unsigned cxb0 = (unsigned)(((0 + l16) ^ (l & 7)) * 16);
    const unsigned cxb1 = (unsigned)(((4 + l16) ^ (l & 7)) * 16);
    const unsigned aB0 = lds_u32(&lds[0][wm][0]) + (unsigned)(lr * 128);
    const unsigned bB0 = lds_u32(&lds[0][2 + (wn >> 1)][0]) + (unsigned)((wn & 1) * 8192 + lr * 128);
    const unsigned adA00 = aB0 + cxb0, adA01 = aB0 + cxb1;
    const unsigned adA10 = adA00 + 65536, adA11 = adA01 + 65536;
    const unsigned adB00 = bB0 + cxb0, adB01 = bB0 + cxb1;
    const unsigned adB10 = adB00 + 65536, adB11 = adB01 + 65536;

    f32x4 acc[8][4] = {};
    float4 aLo[4][2], aHi[4][2], bC0[2][2], bC1[2][2];

    auto stage = [&](u16* dst, const u16* srcrow, int kt) {
        const u16* s = srcrow + (size_t)kt * 64;
        __builtin_amdgcn_global_load_lds((const AS1 void*)s, (AS3 void*)dst, 16, 0, 0);
        __builtin_amdgcn_global_load_lds((const AS1 void*)(s + (size_t)64 * K),
                                         (AS3 void*)(dst + 4096), 16, 0, 0);
    };

    // prologue: stage tile0->buf0, tile1->buf1; vmcnt(8) => tile0 landed
    stage(dB0h0, Bb, 0);  stage(dB0h1, BbH, 0);
    stage(dA0h0, Ab, 0);  stage(dA0h1, AbH, 0);
    stage(dB1h0, Bb, 1);  stage(dB1h1, BbH, 1);
    stage(dA1h0, Ab, 1);  stage(dA1h1, AbH, 1);
    asm volatile("s_waitcnt vmcnt(8)" ::: "memory");
    __builtin_amdgcn_s_barrier();
    // issue tile0 fragment reads (bC, aLo): lgkm out = 16
    RD_B4(bC0, adB00, adB01, "0", "2048");
    RD_B4(bC1, adB00, adB01, "4096", "6144");
    RD_A8(aLo, adA00, adA01, "0", "2048", "4096", "6144");

    const int niter = nkt >> 1;
    for (int i = 0; i < niter; ++i) {
        const int T = 2 * i;
        const int k2 = (T + 2 < nkt) ? T + 2 : nkt - 1;
        const int k3 = (T + 3 < nkt) ? T + 3 : nkt - 1;
        // tile T (buf0 cur, buf1 next)
        TILE_BODY(adA00, adA01, adA10, adA11, adB10, adB11,
                  dA0h0, dA0h1, dB0h0, dB0h1, k2);
        // tile T+1 (buf1 cur, buf0 next)
        TILE_BODY(adA10, adA11, adA00, adA01, adB00, adB01,
                  dA1h0, dA1h1, dB1h0, dB1h1, k3);
    }

    // ---- epilogue: drain, LDS bounce, coalesced stores ----
    asm volatile("s_waitcnt vmcnt(0) lgkmcnt(0)" ::: "memory");
    __builtin_amdgcn_s_barrier();

    float cb[4], cw[4];
    const bool isxc = (EPI == 1) && (bcol < DINNER);
    if (isxc) {
        #pragma unroll
        for (int n = 0; n < 4; ++n) {
            const int cg = bcol + wn * 64 + n * 16 + lr;
            cb[n] = conv_b[cg]; cw[n] = conv_w[cg * 4 + 3];
        }
    }
    u16* eb = &lds[0][0][0];   // 256x256 u16 = 128KB
    #pragma unroll
    for (int m = 0; m < 8; ++m)
        #pragma unroll
        for (int n = 0; n < 4; ++n)
            #pragma unroll
            for (int r = 0; r < 4; ++r) {
                const int rl = wm * 128 + m * 16 + l16 * 4 + r;
                const int cl = wn * 64 + n * 16 + lr;
                float v = acc[m][n][r];
                if (EPI == 1) v = isxc ? silu_f(cb[n] + cw[n] * v) : silu_f(v);
                eb[rl * 256 + cl] = f2bf(v);
            }
    __syncthreads();

    if (EPI == 1) {
        u16* base = isxc ? (dst0 + bcol) : (dst1 + (bcol - DINNER));
        #pragma unroll
        for (int it = 0; it < 16; ++it) {
            const int idx = it * 4096 + tid * 8;
            const int r = idx >> 8, c = idx & 255;
            *(uint4*)(base + (size_t)(brow + r) * DINNER + c) = *(const uint4*)(eb + idx);
        }
    } else {
        u16* base = dst0 + ((size_t)blockIdx.z * BATCH) * N + bcol;
        #pragma unroll
        for (int it = 0; it < 16; ++it) {
            const int idx = it * 4096 + tid * 8;
            const int r = idx >> 8, c = idx & 255;
            *(uint4*)(base + (size_t)(brow + r) * N + c) = *(const uint4*)(eb + idx);
        }
    }
}

// ---------------- finish GEMM4: out = sum of 4 bf16 split-K partials ----------------
__global__ __launch_bounds__(256)
void finish4b(const u16* __restrict__ P, float* __restrict__ out) {
    const size_t S = (size_t)BATCH * DIM;
    size_t i8 = ((size_t)blockIdx.x * 256 + threadIdx.x) * 8;
    const size_t stride = (size_t)gridDim.x * 256 * 8;
    for (; i8 < S; i8 += stride) {
        uint4 p0 = *(const uint4*)(P + i8);
        uint4 p1 = *(const uint4*)(P + S + i8);
        uint4 p2 = *(const uint4*)(P + 2 * S + i8);
        uint4 p3 = *(const uint4*)(P + 3 * S + i8);
        float o[8];
        #pragma unroll
        for (int k = 0; k < 4; ++k) {
            unsigned a0 = ((const unsigned*)&p0)[k], a1 = ((const unsigned*)&p1)[k];
            unsigned a2 = ((const unsigned*)&p2)[k], a3 = ((const unsigned*)&p3)[k];
            o[2*k]   = bf2f((u16)a0) + bf2f((u16)a1) + bf2f((u16)a2) + bf2f((u16)a3);
            o[2*k+1] = bf2f((u16)(a0>>16)) + bf2f((u16)(a1>>16)) + bf2f((u16)(a2>>16)) + bf2f((u16)(a3>>16));
        }
        *(float4*)(out + i8)     = make_float4(o[0], o[1], o[2], o[3]);
        *(float4*)(out + i8 + 4) = make_float4(o[4], o[5], o[6], o[7]);
    }
}

// ---------------- GEMM2 split-K: P[ks][96][4096] partials (fp32) ----------------
__global__ __launch_bounds__(256)
void gemm_xproj(const u16* __restrict__ xcb, const u16* __restrict__ Wx,
                float* __restrict__ P)
{
    __shared__ __align__(16) u16 Xs[64 * 64];
    __shared__ __align__(16) u16 Ws[96 * 64];
    const int t = threadIdx.x, w = t >> 6, l = t & 63;
    const int brow = blockIdx.x * 64;
    const int ks = blockIdx.y;
    const int lr = l & 15, l16 = l >> 4;
    const int skk = ((l & 7) ^ (l >> 3)) * 8;
    const u16* Xbase = xcb + (size_t)(brow + (l >> 3)) * DINNER + skk;
    const u16* Wbase = Wx + (size_t)(l >> 3) * DINNER + skk;

    f32x4 acc[6] = {};
    const int kend = ks * 512 + 512;
    for (int k0 = ks * 512; k0 < kend; k0 += 64) {
        #pragma unroll
        for (int c = 0; c < 2; ++c) {
            const int seg = c * 4 + w;
            __builtin_amdgcn_global_load_lds(
                (const AS1 void*)(Xbase + (size_t)seg * 8 * DINNER + k0),
                (AS3 void*)(&Xs[seg * 512]), 16, 0, 0);
        }
        #pragma unroll
        for (int c = 0; c < 3; ++c) {
            const int seg = c * 4 + w;
            __builtin_amdgcn_global_load_lds(
                (const AS1 void*)(Wbase + (size_t)seg * 8 * DINNER + k0),
                (AS3 void*)(&Ws[seg * 512]), 16, 0, 0);
        }
        __syncthreads();
        #pragma unroll
        for (int kk = 0; kk < 2; ++kk) {
            const int ra = w * 16 + lr;
            bf16x8 av = *(const bf16x8*)(&Xs[ra * 64 + (((kk * 4 + l16) ^ (ra & 7)) * 8)]);
            #pragma unroll
            for (int n = 0; n < 6; ++n) {
                const int rb = n * 16 + lr;
                bf16x8 bv = *(const bf16x8*)(&Ws[rb * 64 + (((kk * 4 + l16) ^ (rb & 7)) * 8)]);
                acc[n] = __builtin_amdgcn_mfma_f32_16x16x32_bf16(av, bv, acc[n], 0, 0, 0);
            }
        }
        __syncthreads();
    }
    #pragma unroll
    for (int n = 0; n < 6; ++n)
        #pragma unroll
        for (int r = 0; r < 4; ++r) {
            const int row = brow + w * 16 + l16 * 4 + r;
            const int col = n * 16 + lr;
            P[((size_t)ks * 96 + col) * BATCH + row] = acc[n][r];
        }
}

// ---------------- finish: sum partials -> dtb (bf16), s[b] ----------------
__global__ __launch_bounds__(256)
void finish_xdb(const float* __restrict__ P, u16* __restrict__ dtb, float* __restrict__ sbuf)
{
    const int b = blockIdx.x * 256 + threadIdx.x;
    #pragma unroll 8
    for (int c = 0; c < 64; ++c) {
        float v = P[((size_t)0 * 96 + c) * BATCH + b] + P[((size_t)1 * 96 + c) * BATCH + b]
                + P[((size_t)2 * 96 + c) * BATCH + b] + P[((size_t)3 * 96 + c) * BATCH + b];
        dtb[(size_t)b * 64 + c] = f2bf(v);
    }
    float s = 0.f;
    for (int n = 0; n < 16; ++n) {
        float Bv = 0.f, Cv = 0.f;
        #pragma unroll
        for (int ks = 0; ks < 4; ++ks) {
            Bv += P[((size_t)ks * 96 + 64 + n) * BATCH + b];
            Cv += P[((size_t)ks * 96 + 80 + n) * BATCH + b];
        }
        s += Bv * Cv;
    }
    sbuf[b] = s;
}

// ---------------- GEMM3 + y epilogue ----------------
__global__ __launch_bounds__(256)
void gemm_dt_y(const u16* __restrict__ dtb, const u16* __restrict__ Wdt,
               const float* __restrict__ b_dt, const float* __restrict__ Dskip,
               const float* __restrict__ s,
               const u16* __restrict__ xcb, const u16* __restrict__ szb,
               u16* __restrict__ y)
{
    __shared__ __align__(16) u16 Ds[64 * 64];
    __shared__ __align__(16) u16 Ws[128 * 64];
    const int t = threadIdx.x, w = t >> 6, l = t & 63;
    const int wr = w >> 1, wc = w & 1;
    const int brow = blockIdx.y * 64;
    const int bcol = blockIdx.x * 128;
    const int lr = l & 15, l16 = l >> 4;
    const int skk = ((l & 7) ^ (l >> 3)) * 8;

    {
        const u16* Dbase = dtb + (size_t)(brow + (l >> 3)) * 64 + skk;
        const u16* Wbase = Wdt + (size_t)(bcol + (l >> 3)) * 64 + skk;
        #pragma unroll
        for (int c = 0; c < 2; ++c) {
            const int seg = c * 4 + w;
            __builtin_amdgcn_global_load_lds(
                (const AS1 void*)(Dbase + (size_t)seg * 8 * 64),
                (AS3 void*)(&Ds[seg * 512]), 16, 0, 0);
        }
        #pragma unroll
        for (int c = 0; c < 4; ++c) {
            const int seg = c * 4 + w;
            __builtin_amdgcn_global_load_lds(
                (const AS1 void*)(Wbase + (size_t)seg * 8 * 64),
                (AS3 void*)(&Ws[seg * 512]), 16, 0, 0);
        }
    }
    __syncthreads();

    f32x4 acc[2][4] = {};
    #pragma unroll
    for (int kk = 0; kk < 2; ++kk) {
        bf16x8 av[2], bv[4];
        #pragma unroll
        for (int m = 0; m < 2; ++m) {
            const int r = wr * 32 + m * 16 + lr;
            av[m] = *(const bf16x8*)(&Ds[r * 64 + (((kk * 4 + l16) ^ (r & 7)) * 8)]);
        }
        #pragma unroll
        for (int n = 0; n < 4; ++n) {
            const int r = wc * 64 + n * 16 + lr;
            bv[n] = *(const bf16x8*)(&Ws[r * 64 + (((kk * 4 + l16) ^ (r & 7)) * 8)]);
        }
        #pragma unroll
        for (int m = 0; m < 2; ++m)
            #pragma unroll
            for (int n = 0; n < 4; ++n)
                acc[m][n] = __builtin_amdgcn_mfma_f32_16x16x32_bf16(av[m], bv[n], acc[m][n], 0, 0, 0);
    }

    #pragma unroll
    for (int m = 0; m < 2; ++m)
        #pragma unroll
        for (int n = 0; n < 4; ++n)
            #pragma unroll
            for (int r = 0; r < 4; ++r) {
                const int row = brow + wr * 32 + m * 16 + l16 * 4 + r;
                const int col = bcol + wc * 64 + n * 16 + lr;
                float v = acc[m][n][r] + b_dt[col];
                float dt = (v > 20.f) ? v : log1pf(__expf(v));
                float xcv = bf2f(xcb[(size_t)row * DINNER + col]);
                float szv = bf2f(szb[(size_t)row * DINNER + col]);
                float yv = (dt * s[row] + Dskip[col]) * xcv * szv;
                y[(size_t)row * DINNER + col] = f2bf(yv);
            }
}

extern "C" void kernel_launch(void* const* d_in, const int* in_sizes, int n_in,
                              void* d_out, int out_size, void* d_ws, size_t ws_size,
                              hipStream_t stream) {
    const float* x      = (const float*)d_in[0];
    const float* ln_g   = (const float*)d_in[1];
    const float* ln_b   = (const float*)d_in[2];
    const float* W_in   = (const float*)d_in[3];
    const float* conv_w = (const float*)d_in[4];
    const float* conv_b = (const float*)d_in[5];
    const float* W_xp   = (const float*)d_in[6];
    const float* W_dt   = (const float*)d_in[7];
    const float* b_dt   = (const float*)d_in[8];
    // d_in[9] = A_log : dead (L=1, h0=0)
    const float* Dskip  = (const float*)d_in[10];
    const float* W_out  = (const float*)d_in[11];
    float* out = (float*)d_out;

    char* ws = (char*)d_ws;
    const size_t MB = 1u << 20;
    u16*  P4b     = (u16*)(ws);                   // 32MB bf16 partials (overlay)
    u16*  W_in_b  = (u16*)(ws);                   // 8MB   [dead after GEMM1]
    u16*  xn      = (u16*)(ws + 8 * MB);          // 8MB   [dead after GEMM1]
    u16*  xcb     = (u16*)(ws + 16 * MB);         // 16MB  [dead after gemm_dt_y]
    u16*  szb     = (u16*)(ws + 32 * MB);         // 16MB  [dead after gemm_dt_y]
    float* Pxp    = (float*)(ws + 48 * MB);       // 6MB
    u16*  W_xp_b  = (u16*)(ws + 55 * MB);         // 384KB
    u16*  W_dt_b  = (u16*)(ws + 56 * MB);         // 256KB
    u16*  dtb     = (u16*)(ws + 57 * MB);         // 512KB
    u16*  W_out_b = (u16*)(ws + 64 * MB);         // 4MB
    u16*  yb      = (u16*)(ws + 68 * MB);         // 16MB
    float* sbuf   = (float*)(ws + 84 * MB);       // 16KB

    cvt_ln<<<BATCH + 2048, 256, 0, stream>>>(
        x, ln_g, ln_b, xn,
        (const float4*)W_in,  (ushort4*)W_in_b,  (2 * DINNER * DIM) / 4,
        (const float4*)W_out, (ushort4*)W_out_b, (DIM * DINNER) / 4,
        (const float4*)W_xp,  (ushort4*)W_xp_b,  (96 * DINNER) / 4,
        (const float4*)W_dt,  (ushort4*)W_dt_b,  (DINNER * 64) / 4);

    // GEMM1: xz = xn @ W_in^T (fused conv+silu -> xc, sz)
    gemmP<1><<<dim3(4096 / 256, BATCH / 256, 1), 512, 0, stream>>>(
        xn, W_in_b, 4096, DIM, DIM / 64, xcb, szb, conv_w, conv_b);

    // GEMM2 (split-K x4): partials
    gemm_xproj<<<dim3(BATCH / 64, 4), 256, 0, stream>>>(xcb, W_xp_b, Pxp);

    // finish: dtb bf16 + s[b]
    finish_xdb<<<BATCH / 256, 256, 0, stream>>>(Pxp, dtb, sbuf);

    // GEMM3 + epilogue: y
    gemm_dt_y<<<dim3(DINNER / 128, BATCH / 64), 256, 0, stream>>>(
        dtb, W_dt_b, b_dt, Dskip, sbuf, xcb, szb, yb);

    // GEMM4: out = y @ W_out^T, split-K x4, bf16 partials
    gemmP<2><<<dim3(DIM / 256, BATCH / 256, 4), 512, 0, stream>>>(
        yb, W_out_b, DIM, DINNER, (DINNER / 4) / 64, P4b, nullptr, nullptr, nullptr);

    // sum bf16 partials -> fp32 out
    finish4b<<<2048, 256, 0, stream>>>(P4b, out);
}